// Round 1
// baseline (866.778 us; speedup 1.0000x reference)
//
#include <hip/hip_runtime.h>
#include <math.h>

// Problem constants (B=16, H=W=32, C=512, D=128 per group, S=1, R=8)
#define NTOK 16384   // B*H*W
#define NC 512
#define ND 128

__device__ __forceinline__ float sigf(float x){ return 1.f/(1.f+expf(-x)); }

// spatial position p = h*32+w for scan step l in direction g
__device__ __forceinline__ int perm_pos(int g, int l){
  switch(g){
    case 0: return l;
    case 1: return ((l & 31) << 5) | (l >> 5);          // (l%32)*32 + l/32
    case 2: return 1023 - l;
    default:{ int ll = 1023 - l; return ((ll & 31) << 5) | (ll >> 5); }
  }
}

template<int NW>
__device__ __forceinline__ float blk_sum(float v, float* sb){
  #pragma unroll
  for (int o=32;o>0;o>>=1) v += __shfl_down(v,o);
  int lane = threadIdx.x & 63, wv = threadIdx.x >> 6;
  if (lane==0) sb[wv]=v;
  __syncthreads();
  float r = 0.f;
  #pragma unroll
  for (int i=0;i<NW;i++) r += sb[i];
  __syncthreads();
  return r;
}

// ---------------- K1: LayerNorm over C=512 ----------------
__global__ __launch_bounds__(256) void k_ln512(const float* __restrict__ x,
    const float* __restrict__ w, const float* __restrict__ b, float* __restrict__ out){
  __shared__ float sb[4];
  int t = blockIdx.x, tid = threadIdx.x;
  const float* xr = x + (size_t)t*NC;
  float v0 = xr[tid], v1 = xr[tid+256];
  float s  = blk_sum<4>(v0+v1, sb);
  float sq = blk_sum<4>(v0*v0+v1*v1, sb);
  float m = s*(1.f/NC);
  float var = sq*(1.f/NC) - m*m;
  float rs = rsqrtf(var + 1e-5f);
  float* orow = out + (size_t)t*NC;
  orow[tid]     = (v0-m)*rs*w[tid]+b[tid];
  orow[tid+256] = (v1-m)*rs*w[tid+256]+b[tid+256];
}

// ---------------- K2: mean over tokens -> z_avg (B,C) ----------------
__global__ __launch_bounds__(512) void k_colmean(const float* __restrict__ xn,
    float* __restrict__ zavg){
  int b = blockIdx.x, c = threadIdx.x;
  const float* base = xn + (size_t)b*1024*NC + c;
  float acc = 0.f;
  for (int n=0;n<1024;n++) acc += base[(size_t)n*NC];
  zavg[b*NC+c] = acc * (1.f/1024.f);
}

// ---------------- K3: ECA + FC gate ----------------
__global__ __launch_bounds__(512) void k_gate(const float* __restrict__ zavg,
    const float* __restrict__ fcw, const float* __restrict__ fcb,
    const float* __restrict__ ew, float* __restrict__ gate){
  __shared__ float za[NC];
  int b = blockIdx.x, o = threadIdx.x;
  za[o] = zavg[b*NC+o];
  __syncthreads();
  float left  = (o>0)    ? za[o-1] : 0.f;
  float right = (o<NC-1) ? za[o+1] : 0.f;
  float ye = ew[0]*left + ew[1]*za[o] + ew[2]*right;
  float acc = fcb[o];
  const float* wr = fcw + (size_t)o*NC;
  for (int c=0;c<NC;c++) acc += za[c]*wr[c];
  gate[b*NC+o] = sigf(acc + ye);
}

// ---------------- K4: fp32 tiled GEMM  C[t,o] = sum_k A[t,k]*B[o,k] ----------------
// 128x128 tile, BK=16, 256 threads, 8x8 per thread. Split epilogue at nsplit.
__global__ __launch_bounds__(256) void k_gemm(
    const float* __restrict__ A, int lda,
    const float* __restrict__ B, int K,
    float* __restrict__ C0p, int ldc0,
    float* __restrict__ C1p, int ldc1, int nsplit,
    const float* __restrict__ bias){
  __shared__ float As[16][132];
  __shared__ float Bs[16][132];
  const int tid = threadIdx.x;
  const int tx = tid & 15, ty = tid >> 4;
  const int m0 = blockIdx.y * 128, n0 = blockIdx.x * 128;
  const int lr = tid >> 2;          // 0..63
  const int kq = (tid & 3) << 2;    // 0,4,8,12
  float acc[8][8];
  #pragma unroll
  for (int i=0;i<8;i++)
    #pragma unroll
    for (int j=0;j<8;j++) acc[i][j]=0.f;

  for (int k0=0;k0<K;k0+=16){
    float4 a0 = *(const float4*)&A[(size_t)(m0+lr   )*lda + k0 + kq];
    float4 a1 = *(const float4*)&A[(size_t)(m0+lr+64)*lda + k0 + kq];
    float4 b0 = *(const float4*)&B[(size_t)(n0+lr   )*K   + k0 + kq];
    float4 b1 = *(const float4*)&B[(size_t)(n0+lr+64)*K   + k0 + kq];
    As[kq+0][lr]=a0.x; As[kq+1][lr]=a0.y; As[kq+2][lr]=a0.z; As[kq+3][lr]=a0.w;
    As[kq+0][lr+64]=a1.x; As[kq+1][lr+64]=a1.y; As[kq+2][lr+64]=a1.z; As[kq+3][lr+64]=a1.w;
    Bs[kq+0][lr]=b0.x; Bs[kq+1][lr]=b0.y; Bs[kq+2][lr]=b0.z; Bs[kq+3][lr]=b0.w;
    Bs[kq+0][lr+64]=b1.x; Bs[kq+1][lr+64]=b1.y; Bs[kq+2][lr+64]=b1.z; Bs[kq+3][lr+64]=b1.w;
    __syncthreads();
    #pragma unroll
    for (int k=0;k<16;k++){
      float4 av0 = *(const float4*)&As[k][ty*8];
      float4 av1 = *(const float4*)&As[k][ty*8+4];
      float4 bv0 = *(const float4*)&Bs[k][tx*8];
      float4 bv1 = *(const float4*)&Bs[k][tx*8+4];
      float a[8] = {av0.x,av0.y,av0.z,av0.w,av1.x,av1.y,av1.z,av1.w};
      float bb[8] = {bv0.x,bv0.y,bv0.z,bv0.w,bv1.x,bv1.y,bv1.z,bv1.w};
      #pragma unroll
      for (int i=0;i<8;i++)
        #pragma unroll
        for (int j=0;j<8;j++) acc[i][j] += a[i]*bb[j];
    }
    __syncthreads();
  }
  #pragma unroll
  for (int i=0;i<8;i++){
    int r = m0 + ty*8 + i;
    #pragma unroll
    for (int j=0;j<8;j++){
      int c = n0 + tx*8 + j;
      float v = acc[i][j];
      if (bias) v += bias[c];
      if (c < nsplit) C0p[(size_t)r*ldc0 + c] = v;
      else            C1p[(size_t)r*ldc1 + (c-nsplit)] = v;
    }
  }
}

// ---------------- K5: depthwise 3x3 conv + bias + SiLU (channel-last) ----------------
__global__ __launch_bounds__(128) void k_conv(const float* __restrict__ xin,
    const float* __restrict__ cw, const float* __restrict__ cb, float* __restrict__ u){
  int t = blockIdx.x, d = threadIdx.x;
  int b = t >> 10, p = t & 1023, h = p >> 5, w = p & 31;
  const float* wk = cw + (size_t)d*9;
  float acc = cb[d];
  #pragma unroll
  for (int kh=0;kh<3;kh++){
    int hh = h + kh - 1;
    if (hh < 0 || hh >= 32) continue;
    #pragma unroll
    for (int kw=0;kw<3;kw++){
      int w2 = w + kw - 1;
      if (w2 < 0 || w2 >= 32) continue;
      size_t idx = (size_t)((b<<10)|(hh<<5)|w2)*ND + d;
      acc += xin[idx]*wk[kh*3+kw];
    }
  }
  u[(size_t)t*ND+d] = acc * sigf(acc);
}

// ---------------- K6: x_proj (10 outputs) + dt_proj + softplus -> delta, B/C ----------------
__global__ __launch_bounds__(128) void k_xproj(const float* __restrict__ u,
    const float* __restrict__ xpw, const float* __restrict__ dtw,
    const float* __restrict__ dtb, float* __restrict__ delta, float* __restrict__ BC){
  __shared__ float su[ND];
  __shared__ float xs_s[10];
  __shared__ float sb[2];
  int t = blockIdx.x, d = threadIdx.x;
  su[d] = u[(size_t)t*ND + d];
  __syncthreads();
  for (int c=0;c<10;c++){
    float v = su[d]*xpw[c*ND+d];
    #pragma unroll
    for (int o=32;o>0;o>>=1) v += __shfl_down(v,o);
    int lane = d & 63, wv = d >> 6;
    if (lane==0) sb[wv]=v;
    __syncthreads();
    if (d==0) xs_s[c] = sb[0]+sb[1];
    __syncthreads();
  }
  float a = dtb[d];
  #pragma unroll
  for (int r=0;r<8;r++) a += xs_s[r]*dtw[d*8+r];
  float dl = (a > 20.f) ? a : log1pf(expf(a));
  delta[(size_t)t*ND+d] = dl;
  if (d==0) BC[(size_t)t*2]   = xs_s[8];
  if (d==1) BC[(size_t)t*2+1] = xs_s[9];
}

// ---------------- K7: scan pass 1 — per-chunk (prod a, h with h0=0) ----------------
__global__ __launch_bounds__(128) void k_scan1(const float* __restrict__ delta,
    const float* __restrict__ u, const float* __restrict__ BC,
    const float* __restrict__ Alog, int g,
    float* __restrict__ chA, float* __restrict__ chB){
  int d = threadIdx.x;
  int b = blockIdx.x >> 4, ch = blockIdx.x & 15;
  float Ad = -expf(Alog[d]);
  float h = 0.f, ap = 1.f;
  int l0 = ch*64;
  for (int s=0;s<64;s++){
    int l = l0 + s;
    int p = perm_pos(g, l);
    size_t idx = (size_t)((b<<10)|p);
    float dl = delta[idx*ND+d];
    float uv = u[idx*ND+d];
    float Bv = BC[idx*2];
    float av = expf(dl*Ad);
    h = av*h + dl*Bv*uv;
    ap *= av;
  }
  size_t o = (size_t)blockIdx.x*ND + d;
  chA[o]=ap; chB[o]=h;
}

// ---------------- K8: sequential combine over 16 chunks -> h_in per chunk ----------------
__global__ __launch_bounds__(128) void k_scomb(const float* __restrict__ chA,
    const float* __restrict__ chB, float* __restrict__ hIn){
  int b = blockIdx.x, d = threadIdx.x;
  float hrun = 0.f;
  for (int ch=0; ch<16; ch++){
    size_t o = (size_t)((b<<4)|ch)*ND + d;
    hIn[o] = hrun;
    hrun = chA[o]*hrun + chB[o];
  }
}

// ---------------- K9: scan pass 3 — replay with h_in, write y (spatial order) ----------------
__global__ __launch_bounds__(128) void k_scan3(const float* __restrict__ delta,
    const float* __restrict__ u, const float* __restrict__ BC,
    const float* __restrict__ Alog, const float* __restrict__ Dp, int g,
    const float* __restrict__ hIn, float* __restrict__ y){
  int d = threadIdx.x;
  int b = blockIdx.x >> 4, ch = blockIdx.x & 15;
  float Ad = -expf(Alog[d]);
  float Dd = Dp[d];
  float h = hIn[(size_t)blockIdx.x*ND + d];
  int l0 = ch*64;
  for (int s=0;s<64;s++){
    int l = l0 + s;
    int p = perm_pos(g, l);
    size_t idx = (size_t)((b<<10)|p);
    float dl = delta[idx*ND+d];
    float uv = u[idx*ND+d];
    float Bv = BC[idx*2], Cv = BC[idx*2+1];
    float av = expf(dl*Ad);
    h = av*h + dl*Bv*uv;
    y[idx*ND+d] = h*Cv + Dd*uv;   // write at permuted pos == CrossMerge inverse
  }
}

// ---------------- K10: out-LN(128) * SiLU(z) ----------------
__global__ __launch_bounds__(128) void k_yo(const float* __restrict__ y,
    const float* __restrict__ zg, const float* __restrict__ onw,
    const float* __restrict__ onb, float* __restrict__ yo){
  __shared__ float sb[2];
  int t = blockIdx.x, d = threadIdx.x;
  float v = y[(size_t)t*ND+d];
  float s  = blk_sum<2>(v, sb);
  float sq = blk_sum<2>(v*v, sb);
  float m = s*(1.f/ND);
  float var = sq*(1.f/ND) - m*m;
  float yn = (v-m)*rsqrtf(var+1e-5f)*onw[d]+onb[d];
  float zv = zg[(size_t)t*ND+d];
  yo[(size_t)t*ND+d] = yn * zv * sigf(zv);
}

// ---------------- K12: skip*xh*gate then LayerNorm(512) ----------------
__global__ __launch_bounds__(256) void k_gateln(const float* __restrict__ ybuf,
    const float* __restrict__ xn, const float* __restrict__ gate,
    const float* __restrict__ skip, const float* __restrict__ w,
    const float* __restrict__ b, float* __restrict__ out){
  __shared__ float sb[4];
  int t = blockIdx.x, tid = threadIdx.x, bb = t >> 10;
  float ss = skip[0];
  size_t o0 = (size_t)t*NC;
  float v0 = ybuf[o0+tid]    *ss*xn[o0+tid]    *gate[bb*NC+tid];
  float v1 = ybuf[o0+tid+256]*ss*xn[o0+tid+256]*gate[bb*NC+tid+256];
  float s  = blk_sum<4>(v0+v1, sb);
  float sq = blk_sum<4>(v0*v0+v1*v1, sb);
  float m = s*(1.f/NC);
  float var = sq*(1.f/NC) - m*m;
  float rs = rsqrtf(var+1e-5f);
  out[o0+tid]     = (v0-m)*rs*w[tid]+b[tid];
  out[o0+tid+256] = (v1-m)*rs*w[tid+256]+b[tid+256];
}

extern "C" void kernel_launch(void* const* d_in, const int* in_sizes, int n_in,
                              void* d_out, int out_size, void* d_ws, size_t ws_size,
                              hipStream_t stream) {
  const float* x          = (const float*)d_in[0];
  const float* norm_w     = (const float*)d_in[3];
  const float* norm_b     = (const float*)d_in[4];
  const float* fc_w       = (const float*)d_in[5];
  const float* fc_b       = (const float*)d_in[6];
  const float* eca_w      = (const float*)d_in[7];
  const float* skip_scale = (const float*)d_in[8];
  const float* proj_w     = (const float*)d_in[9];
  const float* proj_b     = (const float*)d_in[10];
  const float* in_proj_w  = (const float*)d_in[11];
  const float* conv_w     = (const float*)d_in[12];
  const float* conv_b     = (const float*)d_in[13];
  const float* x_proj_w   = (const float*)d_in[14];
  const float* dt_proj_w  = (const float*)d_in[15];
  const float* dt_proj_b  = (const float*)d_in[16];
  const float* A_log      = (const float*)d_in[17];
  const float* D_param    = (const float*)d_in[18];
  const float* out_norm_w = (const float*)d_in[19];
  const float* out_norm_b = (const float*)d_in[20];
  const float* out_proj_w = (const float*)d_in[21];
  float* out = (float*)d_out;
  float* ws  = (float*)d_ws;

  // workspace layout (floats)
  float* xn    = ws;                       // 8388608
  float* ybuf  = ws + 8388608;             // 8388608
  float* zavg  = ws + 16777216;            // 8192
  float* gate  = zavg + 8192;              // 8192
  float* G     = gate + 8192;              // per-group scratch (reused per group)
  float* xcpre = G;                        // 2097152  (later reused as y)
  float* zg    = G + 2097152;              // 2097152
  float* ubuf  = G + 4194304;              // 2097152
  float* delta = G + 6291456;              // 2097152  (later reused as yo)
  float* BC    = G + 8388608;              // 32768
  float* chA   = BC  + 32768;              // 32768
  float* chB   = chA + 32768;              // 32768
  float* hIn   = chB + 32768;              // 32768
  float* xmn   = G;                        // reuse group scratch after group loop

  k_ln512<<<dim3(NTOK), dim3(256), 0, stream>>>(x, norm_w, norm_b, xn);
  k_colmean<<<dim3(16), dim3(512), 0, stream>>>(xn, zavg);
  k_gate<<<dim3(16), dim3(512), 0, stream>>>(zavg, fc_w, fc_b, eca_w, gate);

  for (int g=0; g<4; ++g){
    // in_proj: (16384 x 256) = xn_g (16384 x 128) @ W^T ; split into xcpre / zg
    k_gemm<<<dim3(2,128), dim3(256), 0, stream>>>(
        xn + g*128, NC, in_proj_w + (size_t)g*256*128, 128,
        xcpre, 128, zg, 128, 128, (const float*)nullptr);
    k_conv<<<dim3(NTOK), dim3(128), 0, stream>>>(
        xcpre, conv_w + (size_t)g*128*9, conv_b + g*128, ubuf);
    k_xproj<<<dim3(NTOK), dim3(128), 0, stream>>>(
        ubuf, x_proj_w + (size_t)g*10*128, dt_proj_w + (size_t)g*128*8,
        dt_proj_b + g*128, delta, BC);
    k_scan1<<<dim3(256), dim3(128), 0, stream>>>(
        delta, ubuf, BC, A_log + g*128, g, chA, chB);
    k_scomb<<<dim3(16), dim3(128), 0, stream>>>(chA, chB, hIn);
    k_scan3<<<dim3(256), dim3(128), 0, stream>>>(
        delta, ubuf, BC, A_log + g*128, D_param + g*128, g, hIn, xcpre /* y */);
    k_yo<<<dim3(NTOK), dim3(128), 0, stream>>>(
        xcpre, zg, out_norm_w + g*128, out_norm_b + g*128, delta /* yo */);
    // out_proj: (16384 x 128) @ W^T -> ybuf channel block g
    k_gemm<<<dim3(1,128), dim3(256), 0, stream>>>(
        delta, 128, out_proj_w + (size_t)g*128*128, 128,
        ybuf + g*128, NC, ybuf, NC, 128, (const float*)nullptr);
  }

  k_gateln<<<dim3(NTOK), dim3(256), 0, stream>>>(
      ybuf, xn, gate, skip_scale, norm_w, norm_b, xmn);
  // final proj: (16384 x 512) @ proj_w^T + proj_b
  k_gemm<<<dim3(4,128), dim3(256), 0, stream>>>(
      xmn, NC, proj_w, NC, out, NC, out, NC, NC, proj_b);
}

// Round 2
// 474.677 us; speedup vs baseline: 1.8260x; 1.8260x over previous
//
#include <hip/hip_runtime.h>
#include <math.h>

// B=16, H=W=32, C=512, D=128/group, S=1, R=8
#define NTOK 16384
#define NC 512
#define ND 128

typedef __attribute__((ext_vector_type(8))) short bf16x8;
typedef __attribute__((ext_vector_type(4))) float f32x4;

__device__ __forceinline__ float sigf(float x){ return 1.f/(1.f+expf(-x)); }
__device__ __forceinline__ float b2f(ushort u){ unsigned x = ((unsigned)u)<<16; return __builtin_bit_cast(float,x); }
__device__ __forceinline__ ushort f2b(float f){
  unsigned u = __builtin_bit_cast(unsigned,f);
  u += 0x7fff + ((u>>16)&1);
  return (ushort)(u>>16);
}

__device__ __forceinline__ int perm_pos(int g, int l){
  switch(g){
    case 0: return l;
    case 1: return ((l & 31) << 5) | (l >> 5);
    case 2: return 1023 - l;
    default:{ int ll = 1023 - l; return ((ll & 31) << 5) | (ll >> 5); }
  }
}

template<int NW>
__device__ __forceinline__ float blk_sum(float v, float* sb){
  #pragma unroll
  for (int o=32;o>0;o>>=1) v += __shfl_down(v,o);
  int lane = threadIdx.x & 63, wv = threadIdx.x >> 6;
  if (lane==0) sb[wv]=v;
  __syncthreads();
  float r = 0.f;
  #pragma unroll
  for (int i=0;i<NW;i++) r += sb[i];
  __syncthreads();
  return r;
}

__device__ __forceinline__ void gload16(const void* g, void* l){
  __builtin_amdgcn_global_load_lds((const __attribute__((address_space(1))) void*)g,
                                   (__attribute__((address_space(3))) void*)l, 16, 0, 0);
}

// ---------------- fp32 -> bf16 convert ----------------
__global__ __launch_bounds__(256) void k_tobf16(const float* __restrict__ s,
    ushort* __restrict__ d, int n){
  int i = blockIdx.x*256 + threadIdx.x;
  if (i < n) d[i] = f2b(s[i]);
}

// ---------------- K1: LayerNorm over C=512, bf16 out ----------------
__global__ __launch_bounds__(256) void k_ln512(const float* __restrict__ x,
    const float* __restrict__ w, const float* __restrict__ b, ushort* __restrict__ out){
  __shared__ float sb[4];
  int t = blockIdx.x, tid = threadIdx.x;
  const float* xr = x + (size_t)t*NC;
  float v0 = xr[tid], v1 = xr[tid+256];
  float s  = blk_sum<4>(v0+v1, sb);
  float sq = blk_sum<4>(v0*v0+v1*v1, sb);
  float m = s*(1.f/NC);
  float var = sq*(1.f/NC) - m*m;
  float rs = rsqrtf(var + 1e-5f);
  ushort* orow = out + (size_t)t*NC;
  orow[tid]     = f2b((v0-m)*rs*w[tid]+b[tid]);
  orow[tid+256] = f2b((v1-m)*rs*w[tid+256]+b[tid+256]);
}

// ---------------- K2: column mean, 2-stage ----------------
__global__ __launch_bounds__(512) void k_cm1(const ushort* __restrict__ xn,
    float* __restrict__ part){
  int c = threadIdx.x;
  const ushort* base = xn + ((size_t)blockIdx.x*32)*NC + c;
  float acc = 0.f;
  for (int n=0;n<32;n++) acc += b2f(base[(size_t)n*NC]);
  part[(size_t)blockIdx.x*NC + c] = acc;
}
__global__ __launch_bounds__(512) void k_cm2(const float* __restrict__ part,
    float* __restrict__ zavg){
  int b = blockIdx.x, c = threadIdx.x;
  float acc = 0.f;
  for (int i=0;i<32;i++) acc += part[(size_t)(b*32+i)*NC + c];
  zavg[b*NC+c] = acc * (1.f/1024.f);
}

// ---------------- K3: ECA + FC gate ----------------
__global__ __launch_bounds__(512) void k_gate(const float* __restrict__ zavg,
    const float* __restrict__ fcw, const float* __restrict__ fcb,
    const float* __restrict__ ew, float* __restrict__ gate){
  __shared__ float za[NC];
  int b = blockIdx.x, o = threadIdx.x;
  za[o] = zavg[b*NC+o];
  __syncthreads();
  float left  = (o>0)    ? za[o-1] : 0.f;
  float right = (o<NC-1) ? za[o+1] : 0.f;
  float ye = ew[0]*left + ew[1]*za[o] + ew[2]*right;
  float acc = fcb[o];
  const float* wr = fcw + (size_t)o*NC;
  for (int c=0;c<NC;c++) acc += za[c]*wr[c];
  gate[b*NC+o] = sigf(acc + ye);
}

// ---------------- K4: bf16 MFMA GEMM  C[m,n] = sum_k A[m,k]*B[n,k] ----------------
// BM=BN=128, BK=64, 256 thr (4 waves, 2x2), m97 structure + T2 st-swizzle.
__global__ __launch_bounds__(256) void k_gemm_bf16(
    const ushort* __restrict__ A, int lda,
    const ushort* __restrict__ Bw, int ldb, int K,
    ushort* __restrict__ C0, int ldc0, ushort* __restrict__ C1, int ldc1, int nsplit,
    float* __restrict__ Cf, int ldcf, const float* __restrict__ bias)
{
  __shared__ __align__(16) ushort Asm[128*64];
  __shared__ __align__(16) ushort Bsm[128*64];
  const int tid = threadIdx.x;
  const int lane = tid & 63, wid = tid >> 6;
  const int wm = wid >> 1, wn = wid & 1;
  const int m0 = blockIdx.y * 128, n0 = blockIdx.x * 128;

  // staging: chunk c = tid + 256*j ; r=c>>3 ; linear LDS slot sb=(c&7)*16 ;
  // global source column byte = sb ^ ((r&7)<<4)  (inverse-swizzled source, rule #21)
  const ushort* ga[4]; const ushort* gb[4]; int ldst[4];
  #pragma unroll
  for (int j=0;j<4;j++){
    int c = tid + 256*j;
    int r = c >> 3;
    int kb = ((c & 7) << 4) ^ ((r & 7) << 4);
    ga[j] = A  + (size_t)(m0 + r)*lda + (kb >> 1);
    gb[j] = Bw + (size_t)(n0 + r)*ldb + (kb >> 1);
    ldst[j] = c * 8; // ushort index, 16B per chunk
  }

  f32x4 acc[4][4];
  #pragma unroll
  for (int i=0;i<4;i++)
    #pragma unroll
    for (int j=0;j<4;j++) acc[i][j] = (f32x4){0.f,0.f,0.f,0.f};

  const int lc = lane & 15;          // frag row/col within 16
  const int kgrp = (lane >> 4) << 4; // k-byte base per lane group

  for (int k0 = 0; k0 < K; k0 += 64){
    #pragma unroll
    for (int j=0;j<4;j++) gload16(ga[j] + k0, Asm + ldst[j]);
    #pragma unroll
    for (int j=0;j<4;j++) gload16(gb[j] + k0, Bsm + ldst[j]);
    __syncthreads();   // compiler drains vmcnt before barrier -> tile ready
    #pragma unroll
    for (int kk=0; kk<2; kk++){
      bf16x8 af[4], bfr[4];
      #pragma unroll
      for (int i=0;i<4;i++){
        int ra = wm*64 + i*16 + lc;
        int kb = kk*64 + kgrp;
        af[i] = *(const bf16x8*)((const char*)Asm + ra*128 + (kb ^ ((ra&7)<<4)));
        int rb = wn*64 + i*16 + lc;
        bfr[i] = *(const bf16x8*)((const char*)Bsm + rb*128 + (kb ^ ((rb&7)<<4)));
      }
      #pragma unroll
      for (int i=0;i<4;i++)
        #pragma unroll
        for (int j=0;j<4;j++)
          acc[i][j] = __builtin_amdgcn_mfma_f32_16x16x32_bf16(af[i], bfr[j], acc[i][j], 0, 0, 0);
    }
    __syncthreads();   // all reads done before next-tile overwrite
  }

  const int lr = (lane >> 4) * 4;
  if (Cf){
    #pragma unroll
    for (int i=0;i<4;i++){
      #pragma unroll
      for (int j=0;j<4;j++){
        int row = m0 + wm*64 + i*16 + lr;
        int col = n0 + wn*64 + j*16 + lc;
        float bv = bias ? bias[col] : 0.f;
        #pragma unroll
        for (int r=0;r<4;r++)
          Cf[(size_t)(row+r)*ldcf + col] = acc[i][j][r] + bv;
      }
    }
  } else {
    #pragma unroll
    for (int i=0;i<4;i++){
      #pragma unroll
      for (int j=0;j<4;j++){
        int row = m0 + wm*64 + i*16 + lr;
        int col = n0 + wn*64 + j*16 + lc;
        #pragma unroll
        for (int r=0;r<4;r++){
          ushort hv = f2b(acc[i][j][r]);
          if (col < nsplit) C0[(size_t)(row+r)*ldc0 + col] = hv;
          else              C1[(size_t)(row+r)*ldc1 + col - nsplit] = hv;
        }
      }
    }
  }
}

// ---------------- K5: depthwise 3x3 conv + bias + SiLU ----------------
__global__ __launch_bounds__(256) void k_conv(const ushort* __restrict__ xin,
    const float* __restrict__ cw, const float* __restrict__ cb, float* __restrict__ u){
  int t = blockIdx.x*2 + (threadIdx.x >> 7);
  int d = threadIdx.x & 127;
  int b = t >> 10, p = t & 1023, h = p >> 5, w = p & 31;
  const float* wk = cw + (size_t)d*9;
  float acc = cb[d];
  #pragma unroll
  for (int kh=0;kh<3;kh++){
    int hh = h + kh - 1;
    if (hh < 0 || hh >= 32) continue;
    #pragma unroll
    for (int kw=0;kw<3;kw++){
      int w2 = w + kw - 1;
      if (w2 < 0 || w2 >= 32) continue;
      size_t idx = (size_t)((b<<10)|(hh<<5)|w2)*ND + d;
      acc += b2f(xin[idx])*wk[kh*3+kw];
    }
  }
  u[(size_t)t*ND+d] = acc * sigf(acc);
}

// ---------------- K6: x_proj + dt_proj + softplus ----------------
__global__ __launch_bounds__(128) void k_xproj(const float* __restrict__ u,
    const float* __restrict__ xpw, const float* __restrict__ dtw,
    const float* __restrict__ dtb, float* __restrict__ delta, float* __restrict__ BC){
  __shared__ float sw[2][10];
  int t = blockIdx.x, d = threadIdx.x;
  int lane = d & 63, wv = d >> 6;
  float uv = u[(size_t)t*ND + d];
  float p[10];
  #pragma unroll
  for (int c=0;c<10;c++) p[c] = uv * xpw[c*ND+d];
  #pragma unroll
  for (int o=32;o>0;o>>=1){
    #pragma unroll
    for (int c=0;c<10;c++) p[c] += __shfl_down(p[c], o);
  }
  if (lane==0){
    #pragma unroll
    for (int c=0;c<10;c++) sw[wv][c] = p[c];
  }
  __syncthreads();
  float xs[10];
  #pragma unroll
  for (int c=0;c<10;c++) xs[c] = sw[0][c] + sw[1][c];
  float a = dtb[d];
  #pragma unroll
  for (int r=0;r<8;r++) a += xs[r]*dtw[d*8+r];
  float dl = (a > 20.f) ? a : log1pf(expf(a));
  delta[(size_t)t*ND+d] = dl;
  if (d==0){ BC[(size_t)t*2] = xs[8]; BC[(size_t)t*2+1] = xs[9]; }
}

// ---------------- K7: scan pass 1 (32 chunks x 32 steps) ----------------
__global__ __launch_bounds__(128) void k_scan1(const float* __restrict__ delta,
    const float* __restrict__ u, const float* __restrict__ BC,
    const float* __restrict__ Alog, int g,
    float* __restrict__ chA, float* __restrict__ chB){
  int d = threadIdx.x;
  int b = blockIdx.x >> 5, ch = blockIdx.x & 31;
  float Ad = -expf(Alog[d]);
  float h = 0.f, ap = 1.f;
  int l0 = ch*32;
  for (int s=0;s<32;s++){
    int pp = perm_pos(g, l0 + s);
    size_t idx = (size_t)((b<<10)|pp);
    float dl = delta[idx*ND+d];
    float uvv = u[idx*ND+d];
    float Bv = BC[idx*2];
    float av = expf(dl*Ad);
    h = av*h + dl*Bv*uvv;
    ap *= av;
  }
  size_t o = (size_t)blockIdx.x*ND + d;
  chA[o]=ap; chB[o]=h;
}

// ---------------- K8: combine over 32 chunks ----------------
__global__ __launch_bounds__(128) void k_scomb(const float* __restrict__ chA,
    const float* __restrict__ chB, float* __restrict__ hIn){
  int b = blockIdx.x, d = threadIdx.x;
  float hrun = 0.f;
  for (int ch=0; ch<32; ch++){
    size_t o = (size_t)((b<<5)|ch)*ND + d;
    hIn[o] = hrun;
    hrun = chA[o]*hrun + chB[o];
  }
}

// ---------------- K9: scan pass 3 ----------------
__global__ __launch_bounds__(128) void k_scan3(const float* __restrict__ delta,
    const float* __restrict__ u, const float* __restrict__ BC,
    const float* __restrict__ Alog, const float* __restrict__ Dp, int g,
    const float* __restrict__ hIn, float* __restrict__ y){
  int d = threadIdx.x;
  int b = blockIdx.x >> 5, ch = blockIdx.x & 31;
  float Ad = -expf(Alog[d]);
  float Dd = Dp[d];
  float h = hIn[(size_t)blockIdx.x*ND + d];
  int l0 = ch*32;
  for (int s=0;s<32;s++){
    int pp = perm_pos(g, l0 + s);
    size_t idx = (size_t)((b<<10)|pp);
    float dl = delta[idx*ND+d];
    float uvv = u[idx*ND+d];
    float Bv = BC[idx*2], Cv = BC[idx*2+1];
    float av = expf(dl*Ad);
    h = av*h + dl*Bv*uvv;
    y[idx*ND+d] = h*Cv + Dd*uvv;
  }
}

// ---------------- K10: out-LN(128) * SiLU(z), bf16 out ----------------
__global__ __launch_bounds__(128) void k_yo(const float* __restrict__ y,
    const ushort* __restrict__ zg, const float* __restrict__ onw,
    const float* __restrict__ onb, ushort* __restrict__ yo){
  __shared__ float sb[2];
  int t = blockIdx.x, d = threadIdx.x;
  float v = y[(size_t)t*ND+d];
  float s  = blk_sum<2>(v, sb);
  float sq = blk_sum<2>(v*v, sb);
  float m = s*(1.f/ND);
  float var = sq*(1.f/ND) - m*m;
  float yn = (v-m)*rsqrtf(var+1e-5f)*onw[d]+onb[d];
  float zv = b2f(zg[(size_t)t*ND+d]);
  yo[(size_t)t*ND+d] = f2b(yn * zv * sigf(zv));
}

// ---------------- K12: skip*xh*gate then LayerNorm(512), bf16 out ----------------
__global__ __launch_bounds__(256) void k_gateln(const ushort* __restrict__ ybuf,
    const ushort* __restrict__ xn, const float* __restrict__ gate,
    const float* __restrict__ skip, const float* __restrict__ w,
    const float* __restrict__ b, ushort* __restrict__ out){
  __shared__ float sb[4];
  int t = blockIdx.x, tid = threadIdx.x, bb = t >> 10;
  float ss = skip[0];
  size_t o0 = (size_t)t*NC;
  float v0 = b2f(ybuf[o0+tid])    *ss*b2f(xn[o0+tid])    *gate[bb*NC+tid];
  float v1 = b2f(ybuf[o0+tid+256])*ss*b2f(xn[o0+tid+256])*gate[bb*NC+tid+256];
  float s  = blk_sum<4>(v0+v1, sb);
  float sq = blk_sum<4>(v0*v0+v1*v1, sb);
  float m = s*(1.f/NC);
  float var = sq*(1.f/NC) - m*m;
  float rs = rsqrtf(var+1e-5f);
  out[o0+tid]     = f2b((v0-m)*rs*w[tid]+b[tid]);
  out[o0+tid+256] = f2b((v1-m)*rs*w[tid+256]+b[tid+256]);
}

extern "C" void kernel_launch(void* const* d_in, const int* in_sizes, int n_in,
                              void* d_out, int out_size, void* d_ws, size_t ws_size,
                              hipStream_t stream) {
  const float* x          = (const float*)d_in[0];
  const float* norm_w     = (const float*)d_in[3];
  const float* norm_b     = (const float*)d_in[4];
  const float* fc_w       = (const float*)d_in[5];
  const float* fc_b       = (const float*)d_in[6];
  const float* eca_w      = (const float*)d_in[7];
  const float* skip_scale = (const float*)d_in[8];
  const float* proj_w     = (const float*)d_in[9];
  const float* proj_b     = (const float*)d_in[10];
  const float* in_proj_w  = (const float*)d_in[11];
  const float* conv_w     = (const float*)d_in[12];
  const float* conv_b     = (const float*)d_in[13];
  const float* x_proj_w   = (const float*)d_in[14];
  const float* dt_proj_w  = (const float*)d_in[15];
  const float* dt_proj_b  = (const float*)d_in[16];
  const float* A_log      = (const float*)d_in[17];
  const float* D_param    = (const float*)d_in[18];
  const float* out_norm_w = (const float*)d_in[19];
  const float* out_norm_b = (const float*)d_in[20];
  const float* out_proj_w = (const float*)d_in[21];
  float* out = (float*)d_out;
  float* ws  = (float*)d_ws;

  // workspace layout (float units)
  ushort* xn_b   = (ushort*)(ws);                 // 16384*512 bf16  (4.19M fl)
  ushort* ybuf_b = (ushort*)(ws + 4194304);       // 16384*512 bf16
  float*  zavg   = ws + 8388608;                  // 8192
  float*  gatep  = ws + 8396800;                  // 8192
  ushort* wb_in  = (ushort*)(ws + 8404992);       // 131072 bf16
  ushort* wb_out = (ushort*)(ws + 8470528);       // 65536 bf16
  ushort* wb_prj = (ushort*)(ws + 8503296);       // 262144 bf16
  float*  G      = ws + 8634368;                  // group scratch
  ushort* xc_b   = (ushort*)(G);                  // 16384*128 bf16
  ushort* zg_b   = (ushort*)(G + 1048576);        // 16384*128 bf16
  float*  u      = G + 2097152;                   // 16384*128 f32
  float*  delta  = G + 4194304;                   // 16384*128 f32
  float*  y      = G + 6291456;                   // 16384*128 f32
  ushort* yo_b   = (ushort*)(G + 8388608);        // 16384*128 bf16
  float*  BC     = G + 9437184;                   // 32768
  float*  chA    = G + 9469952;                   // 65536
  float*  chB    = G + 9535488;                   // 65536
  float*  hIn    = G + 9601024;                   // 65536
  float*  part   = G;                             // colmean partial (pre-group, 262144)
  ushort* xmn_b  = (ushort*)(G);                  // post-group alias (8.39M bf16)

  k_ln512<<<dim3(NTOK), dim3(256), 0, stream>>>(x, norm_w, norm_b, xn_b);
  k_cm1<<<dim3(512), dim3(512), 0, stream>>>(xn_b, part);
  k_cm2<<<dim3(16), dim3(512), 0, stream>>>(part, zavg);
  k_gate<<<dim3(16), dim3(512), 0, stream>>>(zavg, fc_w, fc_b, eca_w, gatep);

  k_tobf16<<<dim3(512), dim3(256), 0, stream>>>(in_proj_w, wb_in, 131072);
  k_tobf16<<<dim3(256), dim3(256), 0, stream>>>(out_proj_w, wb_out, 65536);
  k_tobf16<<<dim3(1024), dim3(256), 0, stream>>>(proj_w, wb_prj, 262144);

  for (int g=0; g<4; ++g){
    // in_proj: (16384x256) = xn_g (16384x128) @ W^T -> split xc_b / zg_b
    k_gemm_bf16<<<dim3(2,128), dim3(256), 0, stream>>>(
        xn_b + g*128, NC, wb_in + (size_t)g*256*128, 128, 128,
        xc_b, 128, zg_b, 128, 128, (float*)nullptr, 0, (const float*)nullptr);
    k_conv<<<dim3(NTOK/2), dim3(256), 0, stream>>>(
        xc_b, conv_w + (size_t)g*128*9, conv_b + g*128, u);
    k_xproj<<<dim3(NTOK), dim3(128), 0, stream>>>(
        u, x_proj_w + (size_t)g*10*128, dt_proj_w + (size_t)g*128*8,
        dt_proj_b + g*128, delta, BC);
    k_scan1<<<dim3(512), dim3(128), 0, stream>>>(
        delta, u, BC, A_log + g*128, g, chA, chB);
    k_scomb<<<dim3(16), dim3(128), 0, stream>>>(chA, chB, hIn);
    k_scan3<<<dim3(512), dim3(128), 0, stream>>>(
        delta, u, BC, A_log + g*128, D_param + g*128, g, hIn, y);
    k_yo<<<dim3(NTOK), dim3(128), 0, stream>>>(
        y, zg_b, out_norm_w + g*128, out_norm_b + g*128, yo_b);
    // out_proj: (16384x128) @ W^T -> ybuf_b column block g
    k_gemm_bf16<<<dim3(1,128), dim3(256), 0, stream>>>(
        yo_b, 128, wb_out + (size_t)g*128*128, 128, 128,
        ybuf_b + g*128, NC, ybuf_b + g*128, NC, 128,
        (float*)nullptr, 0, (const float*)nullptr);
  }

  k_gateln<<<dim3(NTOK), dim3(256), 0, stream>>>(
      ybuf_b, xn_b, gatep, skip_scale, norm_w, norm_b, xmn_b);
  // final proj: (16384x512) @ proj_w^T + bias -> out (fp32)
  k_gemm_bf16<<<dim3(4,128), dim3(256), 0, stream>>>(
      xmn_b, NC, wb_prj, NC, NC,
      (ushort*)nullptr, 0, (ushort*)nullptr, 0, 0, out, NC, proj_b);
}

// Round 3
// 308.994 us; speedup vs baseline: 2.8052x; 1.5362x over previous
//
#include <hip/hip_runtime.h>
#include <math.h>

// B=16, H=W=32, C=512, D=128/group, S=1, R=8
#define NTOK 16384
#define NC 512
#define ND 128
#define NCH 64   // scan chunks per (b,g)
#define CST 16   // steps per chunk

typedef __attribute__((ext_vector_type(8))) short bf16x8;
typedef __attribute__((ext_vector_type(4))) float f32x4;

__device__ __forceinline__ float sigf(float x){ return 1.f/(1.f+expf(-x)); }
__device__ __forceinline__ float b2f(ushort u){ unsigned x = ((unsigned)u)<<16; return __builtin_bit_cast(float,x); }
__device__ __forceinline__ ushort f2b(float f){
  unsigned u = __builtin_bit_cast(unsigned,f);
  u += 0x7fff + ((u>>16)&1);
  return (ushort)(u>>16);
}

__device__ __forceinline__ int perm_pos(int g, int l){
  switch(g){
    case 0: return l;
    case 1: return ((l & 31) << 5) | (l >> 5);
    case 2: return 1023 - l;
    default:{ int ll = 1023 - l; return ((ll & 31) << 5) | (ll >> 5); }
  }
}

template<int NW>
__device__ __forceinline__ float blk_sum(float v, float* sb){
  #pragma unroll
  for (int o=32;o>0;o>>=1) v += __shfl_down(v,o);
  int lane = threadIdx.x & 63, wv = threadIdx.x >> 6;
  if (lane==0) sb[wv]=v;
  __syncthreads();
  float r = 0.f;
  #pragma unroll
  for (int i=0;i<NW;i++) r += sb[i];
  __syncthreads();
  return r;
}

__device__ __forceinline__ void gload16(const void* g, void* l){
  __builtin_amdgcn_global_load_lds((const __attribute__((address_space(1))) void*)g,
                                   (__attribute__((address_space(3))) void*)l, 16, 0, 0);
}

// ---------------- fp32 -> bf16 convert, 3 arrays in one launch ----------------
__global__ __launch_bounds__(256) void k_tobf16_3(
    const float* __restrict__ s1, int n1, ushort* __restrict__ d1,
    const float* __restrict__ s2, int n2, ushort* __restrict__ d2,
    const float* __restrict__ s3, int n3, ushort* __restrict__ d3){
  int i = blockIdx.x*256 + threadIdx.x;
  if (i < n1) d1[i] = f2b(s1[i]);
  else if (i < n1+n2) d2[i-n1] = f2b(s2[i-n1]);
  else if (i < n1+n2+n3) d3[i-n1-n2] = f2b(s3[i-n1-n2]);
}

// ---------------- K1: LayerNorm over C=512, bf16 out ----------------
__global__ __launch_bounds__(256) void k_ln512(const float* __restrict__ x,
    const float* __restrict__ w, const float* __restrict__ b, ushort* __restrict__ out){
  __shared__ float sb[4];
  int t = blockIdx.x, tid = threadIdx.x;
  const float* xr = x + (size_t)t*NC;
  float v0 = xr[tid], v1 = xr[tid+256];
  float s  = blk_sum<4>(v0+v1, sb);
  float sq = blk_sum<4>(v0*v0+v1*v1, sb);
  float m = s*(1.f/NC);
  float var = sq*(1.f/NC) - m*m;
  float rs = rsqrtf(var + 1e-5f);
  ushort* orow = out + (size_t)t*NC;
  orow[tid]     = f2b((v0-m)*rs*w[tid]+b[tid]);
  orow[tid+256] = f2b((v1-m)*rs*w[tid+256]+b[tid+256]);
}

// ---------------- K2: column mean, 2-stage ----------------
__global__ __launch_bounds__(512) void k_cm1(const ushort* __restrict__ xn,
    float* __restrict__ part){
  int c = threadIdx.x;
  const ushort* base = xn + ((size_t)blockIdx.x*32)*NC + c;
  float acc = 0.f;
  for (int n=0;n<32;n++) acc += b2f(base[(size_t)n*NC]);
  part[(size_t)blockIdx.x*NC + c] = acc;
}
__global__ __launch_bounds__(512) void k_cm2(const float* __restrict__ part,
    float* __restrict__ zavg){
  int b = blockIdx.x, c = threadIdx.x;
  float acc = 0.f;
  for (int i=0;i<32;i++) acc += part[(size_t)(b*32+i)*NC + c];
  zavg[b*NC+c] = acc * (1.f/1024.f);
}

// ---------------- K3: ECA + FC gate ----------------
__global__ __launch_bounds__(512) void k_gate(const float* __restrict__ zavg,
    const float* __restrict__ fcw, const float* __restrict__ fcb,
    const float* __restrict__ ew, float* __restrict__ gate){
  __shared__ float za[NC];
  int b = blockIdx.x, o = threadIdx.x;
  za[o] = zavg[b*NC+o];
  __syncthreads();
  float left  = (o>0)    ? za[o-1] : 0.f;
  float right = (o<NC-1) ? za[o+1] : 0.f;
  float ye = ew[0]*left + ew[1]*za[o] + ew[2]*right;
  float acc = fcb[o];
  const float* wr = fcw + (size_t)o*NC;
  for (int c=0;c<NC;c++) acc += za[c]*wr[c];
  gate[b*NC+o] = sigf(acc + ye);
}

// ---------------- K4: bf16 MFMA GEMM, z-batched ----------------
// C[m,n] = sum_k A[m,k]*B[n,k]; BM=BN=128, BK=64, 4 waves 2x2, T2 swizzle.
__global__ __launch_bounds__(256) void k_gemm_bf16(
    const ushort* __restrict__ A, int lda, long sAz,
    const ushort* __restrict__ Bw, int ldb, long sBz, int K,
    ushort* __restrict__ C0, int ldc0, ushort* __restrict__ C1, int ldc1,
    int nsplit, long sCz,
    float* __restrict__ Cf, int ldcf, const float* __restrict__ bias)
{
  __shared__ __align__(16) ushort Asm[128*64];
  __shared__ __align__(16) ushort Bsm[128*64];
  const int z = blockIdx.z;
  A  += (size_t)z*sAz;
  Bw += (size_t)z*sBz;
  if (C0) C0 += (size_t)z*sCz;
  if (C1) C1 += (size_t)z*sCz;
  const int tid = threadIdx.x;
  const int lane = tid & 63, wid = tid >> 6;
  const int wm = wid >> 1, wn = wid & 1;
  const int m0 = blockIdx.y * 128, n0 = blockIdx.x * 128;

  const ushort* ga[4]; const ushort* gb[4]; int ldst[4];
  #pragma unroll
  for (int j=0;j<4;j++){
    int c = tid + 256*j;
    int r = c >> 3;
    int kb = ((c & 7) << 4) ^ ((r & 7) << 4);
    ga[j] = A  + (size_t)(m0 + r)*lda + (kb >> 1);
    gb[j] = Bw + (size_t)(n0 + r)*ldb + (kb >> 1);
    ldst[j] = c * 8;
  }

  f32x4 acc[4][4];
  #pragma unroll
  for (int i=0;i<4;i++)
    #pragma unroll
    for (int j=0;j<4;j++) acc[i][j] = (f32x4){0.f,0.f,0.f,0.f};

  const int lc = lane & 15;
  const int kgrp = (lane >> 4) << 4;

  for (int k0 = 0; k0 < K; k0 += 64){
    #pragma unroll
    for (int j=0;j<4;j++) gload16(ga[j] + k0, Asm + ldst[j]);
    #pragma unroll
    for (int j=0;j<4;j++) gload16(gb[j] + k0, Bsm + ldst[j]);
    __syncthreads();
    #pragma unroll
    for (int kk=0; kk<2; kk++){
      bf16x8 af[4], bfr[4];
      #pragma unroll
      for (int i=0;i<4;i++){
        int ra = wm*64 + i*16 + lc;
        int kb = kk*64 + kgrp;
        af[i] = *(const bf16x8*)((const char*)Asm + ra*128 + (kb ^ ((ra&7)<<4)));
        int rb = wn*64 + i*16 + lc;
        bfr[i] = *(const bf16x8*)((const char*)Bsm + rb*128 + (kb ^ ((rb&7)<<4)));
      }
      #pragma unroll
      for (int i=0;i<4;i++)
        #pragma unroll
        for (int j=0;j<4;j++)
          acc[i][j] = __builtin_amdgcn_mfma_f32_16x16x32_bf16(af[i], bfr[j], acc[i][j], 0, 0, 0);
    }
    __syncthreads();
  }

  const int lr = (lane >> 4) * 4;
  if (Cf){
    #pragma unroll
    for (int i=0;i<4;i++)
      #pragma unroll
      for (int j=0;j<4;j++){
        int row = m0 + wm*64 + i*16 + lr;
        int col = n0 + wn*64 + j*16 + lc;
        float bv = bias ? bias[col] : 0.f;
        #pragma unroll
        for (int r=0;r<4;r++)
          Cf[(size_t)(row+r)*ldcf + col] = acc[i][j][r] + bv;
      }
  } else {
    #pragma unroll
    for (int i=0;i<4;i++)
      #pragma unroll
      for (int j=0;j<4;j++){
        int row = m0 + wm*64 + i*16 + lr;
        int col = n0 + wn*64 + j*16 + lc;
        #pragma unroll
        for (int r=0;r<4;r++){
          ushort hv = f2b(acc[i][j][r]);
          if (col < nsplit) C0[(size_t)(row+r)*ldc0 + col] = hv;
          else              C1[(size_t)(row+r)*ldc1 + col - nsplit] = hv;
        }
      }
  }
}

// ---------------- K5: fused depthwise 3x3 conv + SiLU + x_proj ----------------
// block = 1 token x 128 d; g = blockIdx.z. Writes u (f32) and xd (12-padded).
__global__ __launch_bounds__(128) void k_convxp(const ushort* __restrict__ xc,
    const float* __restrict__ cw, const float* __restrict__ cb,
    const float* __restrict__ xpw, float* __restrict__ u, float* __restrict__ xd){
  __shared__ float sw[2][10];
  int t = blockIdx.x, g = blockIdx.z, d = threadIdx.x;
  int b = t >> 10, p = t & 1023, h = p >> 5, w = p & 31;
  const float* wk = cw + (size_t)(g*ND+d)*9;
  float acc = cb[g*ND+d];
  #pragma unroll
  for (int kh=0;kh<3;kh++){
    int hh = h + kh - 1;
    if (hh < 0 || hh >= 32) continue;
    #pragma unroll
    for (int kw=0;kw<3;kw++){
      int w2 = w + kw - 1;
      if (w2 < 0 || w2 >= 32) continue;
      size_t idx = ((size_t)g*NTOK + ((b<<10)|(hh<<5)|w2))*ND + d;
      acc += b2f(xc[idx])*wk[kh*3+kw];
    }
  }
  float uv = acc * sigf(acc);
  size_t base = (size_t)g*NTOK + t;
  u[base*ND + d] = uv;
  // x_proj: 10 reductions over d
  int lane = d & 63, wv = d >> 6;
  float pr[10];
  #pragma unroll
  for (int c=0;c<10;c++) pr[c] = uv * xpw[(g*10+c)*ND + d];
  #pragma unroll
  for (int o=32;o>0;o>>=1){
    #pragma unroll
    for (int c=0;c<10;c++) pr[c] += __shfl_down(pr[c], o);
  }
  if (lane==0){
    #pragma unroll
    for (int c=0;c<10;c++) sw[wv][c] = pr[c];
  }
  __syncthreads();
  if (d < 10) xd[base*12 + d] = sw[0][d] + sw[1][d];
}

// ---------------- scan helpers: recompute delta from xd ----------------
struct ScanCtx {
  float Ad, Dd, dtb_d;
  float w[8];
};

__device__ __forceinline__ void scan_step(const ScanCtx& c, float uv,
    const float4& x0, const float4& x1, float Bv,
    float& h, float& ap, float& dl_out, float& av_out){
  float a = c.dtb_d;
  a = fmaf(x0.x, c.w[0], a); a = fmaf(x0.y, c.w[1], a);
  a = fmaf(x0.z, c.w[2], a); a = fmaf(x0.w, c.w[3], a);
  a = fmaf(x1.x, c.w[4], a); a = fmaf(x1.y, c.w[5], a);
  a = fmaf(x1.z, c.w[6], a); a = fmaf(x1.w, c.w[7], a);
  float dl = (a > 20.f) ? a : log1pf(expf(a));
  float av = expf(dl * c.Ad);
  h = fmaf(av, h, dl*Bv*uv);
  ap *= av;
  dl_out = dl; av_out = av;
}

// ---------------- K6: scan pass 1 — per-chunk summaries ----------------
__global__ __launch_bounds__(128) void k_scan1(const float* __restrict__ u,
    const float* __restrict__ xd, const float* __restrict__ Alog,
    const float* __restrict__ dtw, const float* __restrict__ dtb,
    float* __restrict__ chA, float* __restrict__ chB){
  int d = threadIdx.x, g = blockIdx.z;
  int b = blockIdx.x >> 6, ch = blockIdx.x & 63;
  ScanCtx c;
  c.Ad = -expf(Alog[g*ND+d]);
  c.dtb_d = dtb[g*ND+d];
  const float4* wr = (const float4*)(dtw + (size_t)(g*ND+d)*8);
  float4 w0 = wr[0], w1 = wr[1];
  c.w[0]=w0.x;c.w[1]=w0.y;c.w[2]=w0.z;c.w[3]=w0.w;
  c.w[4]=w1.x;c.w[5]=w1.y;c.w[6]=w1.z;c.w[7]=w1.w;
  float h = 0.f, ap = 1.f;
  int l0 = ch*CST;
  #pragma unroll 4
  for (int s=0;s<CST;s++){
    int pp = perm_pos(g, l0 + s);
    size_t base = (size_t)g*NTOK + ((b<<10)|pp);
    float uv = u[base*ND + d];
    const float4* xr = (const float4*)(xd + base*12);
    float4 x0 = xr[0], x1 = xr[1], x2 = xr[2];
    float dl_o, av_o;
    scan_step(c, uv, x0, x1, x2.x, h, ap, dl_o, av_o);
  }
  size_t o = (((size_t)g*16 + b)*NCH + ch)*ND + d;
  chA[o]=ap; chB[o]=h;
}

// ---------------- K7: combine over chunks ----------------
__global__ __launch_bounds__(128) void k_scomb(const float* __restrict__ chA,
    const float* __restrict__ chB, float* __restrict__ hIn){
  int b = blockIdx.x, g = blockIdx.z, d = threadIdx.x;
  float hrun = 0.f;
  for (int ch=0; ch<NCH; ch++){
    size_t o = (((size_t)g*16 + b)*NCH + ch)*ND + d;
    hIn[o] = hrun;
    hrun = chA[o]*hrun + chB[o];
  }
}

// ---------------- K8: scan pass 3 — replay, write y ----------------
__global__ __launch_bounds__(128) void k_scan3(const float* __restrict__ u,
    const float* __restrict__ xd, const float* __restrict__ Alog,
    const float* __restrict__ dtw, const float* __restrict__ dtb,
    const float* __restrict__ Dp, const float* __restrict__ hIn,
    float* __restrict__ y){
  int d = threadIdx.x, g = blockIdx.z;
  int b = blockIdx.x >> 6, ch = blockIdx.x & 63;
  ScanCtx c;
  c.Ad = -expf(Alog[g*ND+d]);
  c.dtb_d = dtb[g*ND+d];
  float Dd = Dp[g*ND+d];
  const float4* wr = (const float4*)(dtw + (size_t)(g*ND+d)*8);
  float4 w0 = wr[0], w1 = wr[1];
  c.w[0]=w0.x;c.w[1]=w0.y;c.w[2]=w0.z;c.w[3]=w0.w;
  c.w[4]=w1.x;c.w[5]=w1.y;c.w[6]=w1.z;c.w[7]=w1.w;
  float h = hIn[(((size_t)g*16 + b)*NCH + (blockIdx.x & 63))*ND + d];
  float ap = 1.f;
  int l0 = ch*CST;
  #pragma unroll 4
  for (int s=0;s<CST;s++){
    int pp = perm_pos(g, l0 + s);
    size_t base = (size_t)g*NTOK + ((b<<10)|pp);
    float uv = u[base*ND + d];
    const float4* xr = (const float4*)(xd + base*12);
    float4 x0 = xr[0], x1 = xr[1], x2 = xr[2];
    float dl_o, av_o;
    scan_step(c, uv, x0, x1, x2.x, h, ap, dl_o, av_o);
    y[base*ND + d] = fmaf(h, x2.y, Dd*uv);
  }
}

// ---------------- K9: out-LN(128) * SiLU(z), bf16 out ----------------
__global__ __launch_bounds__(128) void k_yo(const float* __restrict__ y,
    const ushort* __restrict__ zg, const float* __restrict__ onw,
    const float* __restrict__ onb, ushort* __restrict__ yo){
  __shared__ float sb[2];
  int t = blockIdx.x, g = blockIdx.z, d = threadIdx.x;
  size_t base = (size_t)g*NTOK + t;
  float v = y[base*ND+d];
  float s  = blk_sum<2>(v, sb);
  float sq = blk_sum<2>(v*v, sb);
  float m = s*(1.f/ND);
  float var = sq*(1.f/ND) - m*m;
  float yn = (v-m)*rsqrtf(var+1e-5f)*onw[g*ND+d]+onb[g*ND+d];
  float zv = b2f(zg[base*ND+d]);
  yo[base*ND+d] = f2b(yn * zv * sigf(zv));
}

// ---------------- K10: skip*xh*gate then LayerNorm(512), bf16 out ----------------
__global__ __launch_bounds__(256) void k_gateln(const ushort* __restrict__ ybuf,
    const ushort* __restrict__ xn, const float* __restrict__ gate,
    const float* __restrict__ skip, const float* __restrict__ w,
    const float* __restrict__ b, ushort* __restrict__ out){
  __shared__ float sb[4];
  int t = blockIdx.x, tid = threadIdx.x, bb = t >> 10;
  float ss = skip[0];
  size_t o0 = (size_t)t*NC;
  float v0 = b2f(ybuf[o0+tid])    *ss*b2f(xn[o0+tid])    *gate[bb*NC+tid];
  float v1 = b2f(ybuf[o0+tid+256])*ss*b2f(xn[o0+tid+256])*gate[bb*NC+tid+256];
  float s  = blk_sum<4>(v0+v1, sb);
  float sq = blk_sum<4>(v0*v0+v1*v1, sb);
  float m = s*(1.f/NC);
  float var = sq*(1.f/NC) - m*m;
  float rs = rsqrtf(var+1e-5f);
  out[o0+tid]     = f2b((v0-m)*rs*w[tid]+b[tid]);
  out[o0+tid+256] = f2b((v1-m)*rs*w[tid+256]+b[tid+256]);
}

extern "C" void kernel_launch(void* const* d_in, const int* in_sizes, int n_in,
                              void* d_out, int out_size, void* d_ws, size_t ws_size,
                              hipStream_t stream) {
  const float* x          = (const float*)d_in[0];
  const float* norm_w     = (const float*)d_in[3];
  const float* norm_b     = (const float*)d_in[4];
  const float* fc_w       = (const float*)d_in[5];
  const float* fc_b       = (const float*)d_in[6];
  const float* eca_w      = (const float*)d_in[7];
  const float* skip_scale = (const float*)d_in[8];
  const float* proj_w     = (const float*)d_in[9];
  const float* proj_b     = (const float*)d_in[10];
  const float* in_proj_w  = (const float*)d_in[11];
  const float* conv_w     = (const float*)d_in[12];
  const float* conv_b     = (const float*)d_in[13];
  const float* x_proj_w   = (const float*)d_in[14];
  const float* dt_proj_w  = (const float*)d_in[15];
  const float* dt_proj_b  = (const float*)d_in[16];
  const float* A_log      = (const float*)d_in[17];
  const float* D_param    = (const float*)d_in[18];
  const float* out_norm_w = (const float*)d_in[19];
  const float* out_norm_b = (const float*)d_in[20];
  const float* out_proj_w = (const float*)d_in[21];
  float* out = (float*)d_out;
  float* ws  = (float*)d_ws;

  // ---- workspace layout (float units); ws_size ~= 256 MiB ----
  ushort* xn_b   = (ushort*)(ws);                  // [0, 4194304)
  ushort* ybuf_b = (ushort*)(ws + 4194304);        // [4194304, 8388608)
  ushort* xc4    = (ushort*)(ws + 8388608);        // [8388608, 12582912)
  ushort* zg4    = (ushort*)(ws + 12582912);       // [12582912, 16777216)
  ushort* yo4    = (ushort*)(ws + 16777216);       // [16777216, 20971520)
  float*  u4     = ws + 20971520;                  // [20971520, 29360128)
  float*  y4     = ws + 29360128;                  // [29360128, 37748736)
  float*  xd4    = ws + 37748736;                  // [37748736, 38535168) 16384*12*4
  float*  chA    = ws + 38535168;                  // 4*16*64*128 = 524288
  float*  chB    = ws + 39059456;
  float*  hIn    = ws + 39583744;
  float*  zavg   = ws + 40108032;                  // 8192
  float*  gatep  = ws + 40116224;                  // 8192
  float*  part   = ws + 40124416;                  // 262144
  ushort* wb_in  = (ushort*)(ws + 40386560);       // 131072 bf16
  ushort* wb_out = (ushort*)(ws + 40452096);       // 65536 bf16
  ushort* wb_prj = (ushort*)(ws + 40484864);       // 262144 bf16
  ushort* xmn_b  = (ushort*)(ws + 40615936);       // 16384*512 bf16
  // end: 44810240 floats = 179 MB

  k_ln512<<<dim3(NTOK), dim3(256), 0, stream>>>(x, norm_w, norm_b, xn_b);
  k_cm1<<<dim3(512), dim3(512), 0, stream>>>(xn_b, part);
  k_cm2<<<dim3(16), dim3(512), 0, stream>>>(part, zavg);
  k_gate<<<dim3(16), dim3(512), 0, stream>>>(zavg, fc_w, fc_b, eca_w, gatep);
  k_tobf16_3<<<dim3((131072+65536+262144+255)/256), dim3(256), 0, stream>>>(
      in_proj_w, 131072, wb_in, out_proj_w, 65536, wb_out, proj_w, 262144, wb_prj);

  // in_proj (batched over g): (16384x256) = xn_g @ W^T -> xc4 / zg4
  k_gemm_bf16<<<dim3(2,128,4), dim3(256), 0, stream>>>(
      xn_b, NC, 128, wb_in, 128, 256*128, 128,
      xc4, 128, zg4, 128, 128, (long)NTOK*128,
      (float*)nullptr, 0, (const float*)nullptr);

  k_convxp<<<dim3(NTOK,1,4), dim3(128), 0, stream>>>(
      xc4, conv_w, conv_b, x_proj_w, u4, xd4);

  k_scan1<<<dim3(16*NCH,1,4), dim3(128), 0, stream>>>(
      u4, xd4, A_log, dt_proj_w, dt_proj_b, chA, chB);
  k_scomb<<<dim3(16,1,4), dim3(128), 0, stream>>>(chA, chB, hIn);
  k_scan3<<<dim3(16*NCH,1,4), dim3(128), 0, stream>>>(
      u4, xd4, A_log, dt_proj_w, dt_proj_b, D_param, hIn, y4);

  k_yo<<<dim3(NTOK,1,4), dim3(128), 0, stream>>>(
      y4, zg4, out_norm_w, out_norm_b, yo4);

  // out_proj (batched): (16384x128) @ W^T -> ybuf column block g
  k_gemm_bf16<<<dim3(1,128,4), dim3(256), 0, stream>>>(
      yo4, 128, (long)NTOK*128, wb_out, 128, 128*128, 128,
      ybuf_b, NC, ybuf_b, NC, 1<<30, 128,
      (float*)nullptr, 0, (const float*)nullptr);

  k_gateln<<<dim3(NTOK), dim3(256), 0, stream>>>(
      ybuf_b, xn_b, gatep, skip_scale, norm_w, norm_b, xmn_b);

  // final proj: (16384x512) @ proj_w^T + bias -> out (fp32)
  k_gemm_bf16<<<dim3(4,128,1), dim3(256), 0, stream>>>(
      xmn_b, NC, 0, wb_prj, NC, 0, NC,
      (ushort*)nullptr, 0, (ushort*)nullptr, 0, 0, 0,
      out, NC, proj_b);
}

// Round 4
// 294.125 us; speedup vs baseline: 2.9470x; 1.0506x over previous
//
#include <hip/hip_runtime.h>
#include <math.h>

// B=16, H=W=32, C=512, D=128/group, S=1, R=8
#define NTOK 16384
#define NC 512
#define ND 128
#define NCH 64   // scan chunks per (b,g)
#define CST 16   // steps per chunk

typedef __attribute__((ext_vector_type(8))) short bf16x8;
typedef __attribute__((ext_vector_type(4))) float f32x4;

__device__ __forceinline__ float sigf(float x){ return 1.f/(1.f+expf(-x)); }
__device__ __forceinline__ float b2f(ushort u){ unsigned x = ((unsigned)u)<<16; return __builtin_bit_cast(float,x); }
__device__ __forceinline__ ushort f2b(float f){
  unsigned u = __builtin_bit_cast(unsigned,f);
  u += 0x7fff + ((u>>16)&1);
  return (ushort)(u>>16);
}

__device__ __forceinline__ int perm_pos(int g, int l){
  switch(g){
    case 0: return l;
    case 1: return ((l & 31) << 5) | (l >> 5);
    case 2: return 1023 - l;
    default:{ int ll = 1023 - l; return ((ll & 31) << 5) | (ll >> 5); }
  }
}

__device__ __forceinline__ void gload16(const void* g, void* l){
  __builtin_amdgcn_global_load_lds((const __attribute__((address_space(1))) void*)g,
                                   (__attribute__((address_space(3))) void*)l, 16, 0, 0);
}

// ---------------- fp32 -> bf16 convert, 3 arrays in one launch ----------------
__global__ __launch_bounds__(256) void k_tobf16_3(
    const float* __restrict__ s1, int n1, ushort* __restrict__ d1,
    const float* __restrict__ s2, int n2, ushort* __restrict__ d2,
    const float* __restrict__ s3, int n3, ushort* __restrict__ d3){
  int i = blockIdx.x*256 + threadIdx.x;
  if (i < n1) d1[i] = f2b(s1[i]);
  else if (i < n1+n2) d2[i-n1] = f2b(s2[i-n1]);
  else if (i < n1+n2+n3) d3[i-n1-n2] = f2b(s3[i-n1-n2]);
}

// ---------------- K1: LayerNorm over C=512, wave-per-token, bf16 out ----------------
__global__ __launch_bounds__(256) void k_ln512(const float* __restrict__ x,
    const float* __restrict__ w, const float* __restrict__ b, ushort* __restrict__ out){
  int wv = threadIdx.x >> 6, lane = threadIdx.x & 63;
  int t = blockIdx.x*4 + wv;
  const float* xr = x + (size_t)t*NC + lane*8;
  float4 a = *(const float4*)xr;
  float4 c = *(const float4*)(xr+4);
  float e[8] = {a.x,a.y,a.z,a.w,c.x,c.y,c.z,c.w};
  float s = 0.f, sq = 0.f;
  #pragma unroll
  for (int i=0;i<8;i++){ s += e[i]; sq += e[i]*e[i]; }
  #pragma unroll
  for (int o=1;o<64;o<<=1){ s += __shfl_xor(s,o); sq += __shfl_xor(sq,o); }
  float m = s*(1.f/NC);
  float var = sq*(1.f/NC) - m*m;
  float rs = rsqrtf(var + 1e-5f);
  const float4* wr = (const float4*)(w + lane*8);
  const float4* br = (const float4*)(b + lane*8);
  float4 w0 = wr[0], w1 = wr[1], b0 = br[0], b1 = br[1];
  float wv8[8] = {w0.x,w0.y,w0.z,w0.w,w1.x,w1.y,w1.z,w1.w};
  float bv8[8] = {b0.x,b0.y,b0.z,b0.w,b1.x,b1.y,b1.z,b1.w};
  bf16x8 o8;
  #pragma unroll
  for (int i=0;i<8;i++) ((ushort*)&o8)[i] = f2b((e[i]-m)*rs*wv8[i]+bv8[i]);
  *(bf16x8*)(out + (size_t)t*NC + lane*8) = o8;
}

// ---------------- K2: column mean, 2-stage ----------------
__global__ __launch_bounds__(512) void k_cm1(const ushort* __restrict__ xn,
    float* __restrict__ part){
  int c = threadIdx.x;
  const ushort* base = xn + ((size_t)blockIdx.x*32)*NC + c;
  float acc = 0.f;
  for (int n=0;n<32;n++) acc += b2f(base[(size_t)n*NC]);
  part[(size_t)blockIdx.x*NC + c] = acc;
}
__global__ __launch_bounds__(512) void k_cm2(const float* __restrict__ part,
    float* __restrict__ zavg){
  int b = blockIdx.x, c = threadIdx.x;
  float acc = 0.f;
  for (int i=0;i<32;i++) acc += part[(size_t)(b*32+i)*NC + c];
  zavg[b*NC+c] = acc * (1.f/1024.f);
}

// ---------------- K3: ECA + FC gate ----------------
__global__ __launch_bounds__(512) void k_gate(const float* __restrict__ zavg,
    const float* __restrict__ fcw, const float* __restrict__ fcb,
    const float* __restrict__ ew, float* __restrict__ gate){
  __shared__ float za[NC];
  int b = blockIdx.x, o = threadIdx.x;
  za[o] = zavg[b*NC+o];
  __syncthreads();
  float left  = (o>0)    ? za[o-1] : 0.f;
  float right = (o<NC-1) ? za[o+1] : 0.f;
  float ye = ew[0]*left + ew[1]*za[o] + ew[2]*right;
  float acc = fcb[o];
  const float* wr = fcw + (size_t)o*NC;
  for (int c=0;c<NC;c++) acc += za[c]*wr[c];
  gate[b*NC+o] = sigf(acc + ye);
}

// ---------------- K4: bf16 MFMA GEMM, z-batched ----------------
__global__ __launch_bounds__(256) void k_gemm_bf16(
    const ushort* __restrict__ A, int lda, long sAz,
    const ushort* __restrict__ Bw, int ldb, long sBz, int K,
    ushort* __restrict__ C0, int ldc0, ushort* __restrict__ C1, int ldc1,
    int nsplit, long sCz,
    float* __restrict__ Cf, int ldcf, const float* __restrict__ bias)
{
  __shared__ __align__(16) ushort Asm[128*64];
  __shared__ __align__(16) ushort Bsm[128*64];
  const int z = blockIdx.z;
  A  += (size_t)z*sAz;
  Bw += (size_t)z*sBz;
  if (C0) C0 += (size_t)z*sCz;
  if (C1) C1 += (size_t)z*sCz;
  const int tid = threadIdx.x;
  const int lane = tid & 63, wid = tid >> 6;
  const int wm = wid >> 1, wn = wid & 1;
  const int m0 = blockIdx.y * 128, n0 = blockIdx.x * 128;

  const ushort* ga[4]; const ushort* gb[4]; int ldst[4];
  #pragma unroll
  for (int j=0;j<4;j++){
    int c = tid + 256*j;
    int r = c >> 3;
    int kb = ((c & 7) << 4) ^ ((r & 7) << 4);
    ga[j] = A  + (size_t)(m0 + r)*lda + (kb >> 1);
    gb[j] = Bw + (size_t)(n0 + r)*ldb + (kb >> 1);
    ldst[j] = c * 8;
  }

  f32x4 acc[4][4];
  #pragma unroll
  for (int i=0;i<4;i++)
    #pragma unroll
    for (int j=0;j<4;j++) acc[i][j] = (f32x4){0.f,0.f,0.f,0.f};

  const int lc = lane & 15;
  const int kgrp = (lane >> 4) << 4;

  for (int k0 = 0; k0 < K; k0 += 64){
    #pragma unroll
    for (int j=0;j<4;j++) gload16(ga[j] + k0, Asm + ldst[j]);
    #pragma unroll
    for (int j=0;j<4;j++) gload16(gb[j] + k0, Bsm + ldst[j]);
    __syncthreads();
    #pragma unroll
    for (int kk=0; kk<2; kk++){
      bf16x8 af[4], bfr[4];
      #pragma unroll
      for (int i=0;i<4;i++){
        int ra = wm*64 + i*16 + lc;
        int kb = kk*64 + kgrp;
        af[i] = *(const bf16x8*)((const char*)Asm + ra*128 + (kb ^ ((ra&7)<<4)));
        int rb = wn*64 + i*16 + lc;
        bfr[i] = *(const bf16x8*)((const char*)Bsm + rb*128 + (kb ^ ((rb&7)<<4)));
      }
      #pragma unroll
      for (int i=0;i<4;i++)
        #pragma unroll
        for (int j=0;j<4;j++)
          acc[i][j] = __builtin_amdgcn_mfma_f32_16x16x32_bf16(af[i], bfr[j], acc[i][j], 0, 0, 0);
    }
    __syncthreads();
  }

  const int lr = (lane >> 4) * 4;
  if (Cf){
    #pragma unroll
    for (int i=0;i<4;i++)
      #pragma unroll
      for (int j=0;j<4;j++){
        int row = m0 + wm*64 + i*16 + lr;
        int col = n0 + wn*64 + j*16 + lc;
        float bv = bias ? bias[col] : 0.f;
        #pragma unroll
        for (int r=0;r<4;r++)
          Cf[(size_t)(row+r)*ldcf + col] = acc[i][j][r] + bv;
      }
  } else {
    #pragma unroll
    for (int i=0;i<4;i++)
      #pragma unroll
      for (int j=0;j<4;j++){
        int row = m0 + wm*64 + i*16 + lr;
        int col = n0 + wn*64 + j*16 + lc;
        #pragma unroll
        for (int r=0;r<4;r++){
          ushort hv = f2b(acc[i][j][r]);
          if (col < nsplit) C0[(size_t)(row+r)*ldc0 + col] = hv;
          else              C1[(size_t)(row+r)*ldc1 + col - nsplit] = hv;
        }
      }
  }
}

// ---------------- K5: fused conv3x3+SiLU + x_proj via MFMA ----------------
// block = 64 tokens x 256 thr; g = blockIdx.z. Writes u (f32) and xd (12-pad).
__global__ __launch_bounds__(256) void k_convxp(const ushort* __restrict__ xc,
    const float* __restrict__ cw, const float* __restrict__ cb,
    const float* __restrict__ xpw, float* __restrict__ u, float* __restrict__ xd){
  __shared__ __align__(16) ushort su[64][136];   // 64 tokens x 128d, padded
  int g = blockIdx.z, tid = threadIdx.x;
  int t0 = blockIdx.x * 64;
  int d = tid & 127;
  const float* wk = cw + (size_t)(g*ND+d)*9;
  float w_[9];
  #pragma unroll
  for (int i=0;i<9;i++) w_[i] = wk[i];
  float bias = cb[g*ND+d];
  const ushort* xcg = xc + (size_t)g*NTOK*ND;

  for (int rep=0; rep<32; rep++){
    int lt = rep*2 + (tid>>7);
    int t = t0 + lt;
    int b = t >> 10, p = t & 1023, h = p >> 5, w = p & 31;
    float acc = bias;
    #pragma unroll
    for (int kh=0;kh<3;kh++){
      int hh = h + kh - 1;
      if (hh < 0 || hh >= 32) continue;
      #pragma unroll
      for (int kw=0;kw<3;kw++){
        int w2 = w + kw - 1;
        if (w2 < 0 || w2 >= 32) continue;
        acc += b2f(xcg[(size_t)((b<<10)|(hh<<5)|w2)*ND + d]) * w_[kh*3+kw];
      }
    }
    float uv = acc * sigf(acc);
    u[((size_t)g*NTOK + t)*ND + d] = uv;
    su[lt][d] = f2b(uv);
  }
  __syncthreads();

  // x_proj: per wave, 16 tokens x 16 outputs (10 real), K=128 via 4 MFMAs
  int lane = tid & 63, wv = tid >> 6;
  int c = lane & 15;
  int kg = (lane >> 4) * 8;
  f32x4 acc4 = (f32x4){0.f,0.f,0.f,0.f};
  const float* xr_base = xpw + (size_t)(g*10 + (c < 10 ? c : 0))*128;
  #pragma unroll
  for (int ks=0; ks<4; ks++){
    bf16x8 af = *(const bf16x8*)&su[wv*16 + (lane & 15)][ks*32 + kg];
    const float* xr = xr_base + ks*32 + kg;
    bf16x8 bfv;
    #pragma unroll
    for (int j=0;j<8;j++) ((ushort*)&bfv)[j] = (c < 10) ? f2b(xr[j]) : (ushort)0;
    acc4 = __builtin_amdgcn_mfma_f32_16x16x32_bf16(af, bfv, acc4, 0, 0, 0);
  }
  if (c < 10){
    #pragma unroll
    for (int r=0;r<4;r++){
      int row = (lane >> 4)*4 + r;
      int t = t0 + wv*16 + row;
      xd[((size_t)g*NTOK + t)*12 + c] = acc4[r];
    }
  }
}

// ---------------- scan helpers ----------------
struct ScanCtx {
  float Ad, dtb_d;
  float w[8];
};

__device__ __forceinline__ void scan_step(const ScanCtx& c, float uv,
    const float4& x0, const float4& x1, float Bv,
    float& h, float& ap){
  float a = c.dtb_d;
  a = fmaf(x0.x, c.w[0], a); a = fmaf(x0.y, c.w[1], a);
  a = fmaf(x0.z, c.w[2], a); a = fmaf(x0.w, c.w[3], a);
  a = fmaf(x1.x, c.w[4], a); a = fmaf(x1.y, c.w[5], a);
  a = fmaf(x1.z, c.w[6], a); a = fmaf(x1.w, c.w[7], a);
  float dl = (a > 20.f) ? a : log1pf(expf(a));
  float av = expf(dl * c.Ad);
  h = fmaf(av, h, dl*Bv*uv);
  ap *= av;
}

// ---------------- K6: scan pass 1 ----------------
__global__ __launch_bounds__(128) void k_scan1(const float* __restrict__ u,
    const float* __restrict__ xd, const float* __restrict__ Alog,
    const float* __restrict__ dtw, const float* __restrict__ dtb,
    float* __restrict__ chA, float* __restrict__ chB){
  int d = threadIdx.x, g = blockIdx.z;
  int b = blockIdx.x >> 6, ch = blockIdx.x & 63;
  ScanCtx c;
  c.Ad = -expf(Alog[g*ND+d]);
  c.dtb_d = dtb[g*ND+d];
  const float4* wr = (const float4*)(dtw + (size_t)(g*ND+d)*8);
  float4 w0 = wr[0], w1 = wr[1];
  c.w[0]=w0.x;c.w[1]=w0.y;c.w[2]=w0.z;c.w[3]=w0.w;
  c.w[4]=w1.x;c.w[5]=w1.y;c.w[6]=w1.z;c.w[7]=w1.w;
  float h = 0.f, ap = 1.f;
  int l0 = ch*CST;
  #pragma unroll 4
  for (int s=0;s<CST;s++){
    int pp = perm_pos(g, l0 + s);
    size_t base = (size_t)g*NTOK + ((b<<10)|pp);
    float uv = u[base*ND + d];
    const float4* xr = (const float4*)(xd + base*12);
    float4 x0 = xr[0], x1 = xr[1], x2 = xr[2];
    scan_step(c, uv, x0, x1, x2.x, h, ap);
  }
  size_t o = (((size_t)g*16 + b)*NCH + ch)*ND + d;
  chA[o]=ap; chB[o]=h;
}

// ---------------- K7: combine over chunks ----------------
__global__ __launch_bounds__(128) void k_scomb(const float* __restrict__ chA,
    const float* __restrict__ chB, float* __restrict__ hIn){
  int b = blockIdx.x, g = blockIdx.z, d = threadIdx.x;
  float hrun = 0.f;
  for (int ch=0; ch<NCH; ch++){
    size_t o = (((size_t)g*16 + b)*NCH + ch)*ND + d;
    hIn[o] = hrun;
    hrun = chA[o]*hrun + chB[o];
  }
}

// ---------------- K8: scan pass 3 ----------------
__global__ __launch_bounds__(128) void k_scan3(const float* __restrict__ u,
    const float* __restrict__ xd, const float* __restrict__ Alog,
    const float* __restrict__ dtw, const float* __restrict__ dtb,
    const float* __restrict__ Dp, const float* __restrict__ hIn,
    float* __restrict__ y){
  int d = threadIdx.x, g = blockIdx.z;
  int b = blockIdx.x >> 6, ch = blockIdx.x & 63;
  ScanCtx c;
  c.Ad = -expf(Alog[g*ND+d]);
  c.dtb_d = dtb[g*ND+d];
  float Dd = Dp[g*ND+d];
  const float4* wr = (const float4*)(dtw + (size_t)(g*ND+d)*8);
  float4 w0 = wr[0], w1 = wr[1];
  c.w[0]=w0.x;c.w[1]=w0.y;c.w[2]=w0.z;c.w[3]=w0.w;
  c.w[4]=w1.x;c.w[5]=w1.y;c.w[6]=w1.z;c.w[7]=w1.w;
  float h = hIn[(((size_t)g*16 + b)*NCH + ch)*ND + d];
  float ap = 1.f;
  int l0 = ch*CST;
  #pragma unroll 4
  for (int s=0;s<CST;s++){
    int pp = perm_pos(g, l0 + s);
    size_t base = (size_t)g*NTOK + ((b<<10)|pp);
    float uv = u[base*ND + d];
    const float4* xr = (const float4*)(xd + base*12);
    float4 x0 = xr[0], x1 = xr[1], x2 = xr[2];
    scan_step(c, uv, x0, x1, x2.x, h, ap);
    y[base*ND + d] = fmaf(h, x2.y, Dd*uv);
  }
}

// ---------------- K9: out-LN(128) * SiLU(z); 16 tokens/block, 16 lanes/token ----------------
__global__ __launch_bounds__(256) void k_yo(const float* __restrict__ y,
    const ushort* __restrict__ zg, const float* __restrict__ onw,
    const float* __restrict__ onb, ushort* __restrict__ yo){
  int tid = threadIdx.x, g = blockIdx.z;
  int lt = tid >> 4, p = tid & 15;
  int t = blockIdx.x*16 + lt;
  size_t base = ((size_t)g*NTOK + t)*ND + p*8;
  float4 a = *(const float4*)(y + base);
  float4 cc = *(const float4*)(y + base + 4);
  float e[8] = {a.x,a.y,a.z,a.w,cc.x,cc.y,cc.z,cc.w};
  float s = 0.f, sq = 0.f;
  #pragma unroll
  for (int i=0;i<8;i++){ s += e[i]; sq += e[i]*e[i]; }
  #pragma unroll
  for (int o=1;o<16;o<<=1){ s += __shfl_xor(s,o); sq += __shfl_xor(sq,o); }
  float m = s*(1.f/ND);
  float var = sq*(1.f/ND) - m*m;
  float rs = rsqrtf(var + 1e-5f);
  const float4* wr = (const float4*)(onw + g*ND + p*8);
  const float4* br = (const float4*)(onb + g*ND + p*8);
  float4 w0 = wr[0], w1 = wr[1], b0 = br[0], b1 = br[1];
  float wv8[8] = {w0.x,w0.y,w0.z,w0.w,w1.x,w1.y,w1.z,w1.w};
  float bv8[8] = {b0.x,b0.y,b0.z,b0.w,b1.x,b1.y,b1.z,b1.w};
  bf16x8 zv = *(const bf16x8*)(zg + base);
  bf16x8 o8;
  #pragma unroll
  for (int i=0;i<8;i++){
    float yn = (e[i]-m)*rs*wv8[i]+bv8[i];
    float z = b2f(((ushort*)&zv)[i]);
    ((ushort*)&o8)[i] = f2b(yn * z * sigf(z));
  }
  *(bf16x8*)(yo + base) = o8;
}

// ---------------- K10: skip*xh*gate then LN(512); wave-per-token ----------------
__global__ __launch_bounds__(256) void k_gateln(const ushort* __restrict__ ybuf,
    const ushort* __restrict__ xn, const float* __restrict__ gate,
    const float* __restrict__ skip, const float* __restrict__ w,
    const float* __restrict__ b, ushort* __restrict__ out){
  int wv = threadIdx.x >> 6, lane = threadIdx.x & 63;
  int t = blockIdx.x*4 + wv, bb = t >> 10;
  float ss = skip[0];
  size_t o0 = (size_t)t*NC + lane*8;
  bf16x8 yv = *(const bf16x8*)(ybuf + o0);
  bf16x8 xv = *(const bf16x8*)(xn + o0);
  const float4* gr = (const float4*)(gate + bb*NC + lane*8);
  float4 g0 = gr[0], g1 = gr[1];
  float gv8[8] = {g0.x,g0.y,g0.z,g0.w,g1.x,g1.y,g1.z,g1.w};
  float e[8];
  float s = 0.f, sq = 0.f;
  #pragma unroll
  for (int i=0;i<8;i++){
    e[i] = b2f(((ushort*)&yv)[i]) * ss * b2f(((ushort*)&xv)[i]) * gv8[i];
    s += e[i]; sq += e[i]*e[i];
  }
  #pragma unroll
  for (int o=1;o<64;o<<=1){ s += __shfl_xor(s,o); sq += __shfl_xor(sq,o); }
  float m = s*(1.f/NC);
  float var = sq*(1.f/NC) - m*m;
  float rs = rsqrtf(var + 1e-5f);
  const float4* wr = (const float4*)(w + lane*8);
  const float4* br = (const float4*)(b + lane*8);
  float4 w0 = wr[0], w1 = wr[1], b0 = br[0], b1 = br[1];
  float wv8[8] = {w0.x,w0.y,w0.z,w0.w,w1.x,w1.y,w1.z,w1.w};
  float bv8[8] = {b0.x,b0.y,b0.z,b0.w,b1.x,b1.y,b1.z,b1.w};
  bf16x8 o8;
  #pragma unroll
  for (int i=0;i<8;i++) ((ushort*)&o8)[i] = f2b((e[i]-m)*rs*wv8[i]+bv8[i]);
  *(bf16x8*)(out + o0) = o8;
}

extern "C" void kernel_launch(void* const* d_in, const int* in_sizes, int n_in,
                              void* d_out, int out_size, void* d_ws, size_t ws_size,
                              hipStream_t stream) {
  const float* x          = (const float*)d_in[0];
  const float* norm_w     = (const float*)d_in[3];
  const float* norm_b     = (const float*)d_in[4];
  const float* fc_w       = (const float*)d_in[5];
  const float* fc_b       = (const float*)d_in[6];
  const float* eca_w      = (const float*)d_in[7];
  const float* skip_scale = (const float*)d_in[8];
  const float* proj_w     = (const float*)d_in[9];
  const float* proj_b     = (const float*)d_in[10];
  const float* in_proj_w  = (const float*)d_in[11];
  const float* conv_w     = (const float*)d_in[12];
  const float* conv_b     = (const float*)d_in[13];
  const float* x_proj_w   = (const float*)d_in[14];
  const float* dt_proj_w  = (const float*)d_in[15];
  const float* dt_proj_b  = (const float*)d_in[16];
  const float* A_log      = (const float*)d_in[17];
  const float* D_param    = (const float*)d_in[18];
  const float* out_norm_w = (const float*)d_in[19];
  const float* out_norm_b = (const float*)d_in[20];
  const float* out_proj_w = (const float*)d_in[21];
  float* out = (float*)d_out;
  float* ws  = (float*)d_ws;

  // ---- workspace layout (float units) ----
  ushort* xn_b   = (ushort*)(ws);                  // 16384*512 bf16
  ushort* ybuf_b = (ushort*)(ws + 4194304);
  ushort* xc4    = (ushort*)(ws + 8388608);        // 4*16384*128 bf16
  ushort* zg4    = (ushort*)(ws + 12582912);
  ushort* yo4    = (ushort*)(ws + 16777216);
  float*  u4     = ws + 20971520;                  // 4*16384*128 f32
  float*  y4     = ws + 29360128;
  float*  xd4    = ws + 37748736;                  // 4*16384*12 f32
  float*  chA    = ws + 38535168;                  // 4*16*64*128
  float*  chB    = ws + 39059456;
  float*  hIn    = ws + 39583744;
  float*  zavg   = ws + 40108032;
  float*  gatep  = ws + 40116224;
  float*  part   = ws + 40124416;
  ushort* wb_in  = (ushort*)(ws + 40386560);
  ushort* wb_out = (ushort*)(ws + 40452096);
  ushort* wb_prj = (ushort*)(ws + 40484864);
  ushort* xmn_b  = (ushort*)(ws + 40615936);

  k_ln512<<<dim3(NTOK/4), dim3(256), 0, stream>>>(x, norm_w, norm_b, xn_b);
  k_cm1<<<dim3(512), dim3(512), 0, stream>>>(xn_b, part);
  k_cm2<<<dim3(16), dim3(512), 0, stream>>>(part, zavg);
  k_gate<<<dim3(16), dim3(512), 0, stream>>>(zavg, fc_w, fc_b, eca_w, gatep);
  k_tobf16_3<<<dim3(1792), dim3(256), 0, stream>>>(
      in_proj_w, 131072, wb_in, out_proj_w, 65536, wb_out, proj_w, 262144, wb_prj);

  // in_proj (batched over g)
  k_gemm_bf16<<<dim3(2,128,4), dim3(256), 0, stream>>>(
      xn_b, NC, 128, wb_in, 128, 256*128, 128,
      xc4, 128, zg4, 128, 128, (long)NTOK*128,
      (float*)nullptr, 0, (const float*)nullptr);

  k_convxp<<<dim3(NTOK/64,1,4), dim3(256), 0, stream>>>(
      xc4, conv_w, conv_b, x_proj_w, u4, xd4);

  k_scan1<<<dim3(16*NCH,1,4), dim3(128), 0, stream>>>(
      u4, xd4, A_log, dt_proj_w, dt_proj_b, chA, chB);
  k_scomb<<<dim3(16,1,4), dim3(128), 0, stream>>>(chA, chB, hIn);
  k_scan3<<<dim3(16*NCH,1,4), dim3(128), 0, stream>>>(
      u4, xd4, A_log, dt_proj_w, dt_proj_b, D_param, hIn, y4);

  k_yo<<<dim3(NTOK/16,1,4), dim3(256), 0, stream>>>(
      y4, zg4, out_norm_w, out_norm_b, yo4);

  // out_proj (batched)
  k_gemm_bf16<<<dim3(1,128,4), dim3(256), 0, stream>>>(
      yo4, 128, (long)NTOK*128, wb_out, 128, 128*128, 128,
      ybuf_b, NC, ybuf_b, NC, 1<<30, 128,
      (float*)nullptr, 0, (const float*)nullptr);

  k_gateln<<<dim3(NTOK/4), dim3(256), 0, stream>>>(
      ybuf_b, xn_b, gatep, skip_scale, norm_w, norm_b, xmn_b);

  // final proj -> out (fp32)
  k_gemm_bf16<<<dim3(4,128,1), dim3(256), 0, stream>>>(
      xmn_b, NC, 0, wb_prj, NC, 0, NC,
      (ushort*)nullptr, 0, (ushort*)nullptr, 0, 0, 0,
      out, NC, proj_b);
}

// Round 5
// 203.071 us; speedup vs baseline: 4.2683x; 1.4484x over previous
//
#include <hip/hip_runtime.h>
#include <math.h>

// B=16, H=W=32, C=512, D=128/group, S=1, R=8
#define NTOK 16384
#define NC 512
#define ND 128
#define NCH 64   // scan chunks per (b,g)
#define CST 16   // steps per chunk

typedef __attribute__((ext_vector_type(8))) short bf16x8;
typedef __attribute__((ext_vector_type(4))) float f32x4;

__device__ __forceinline__ float sigf(float x){ return 1.f/(1.f+expf(-x)); }
__device__ __forceinline__ float b2f(ushort u){ unsigned x = ((unsigned)u)<<16; return __builtin_bit_cast(float,x); }
__device__ __forceinline__ ushort f2b(float f){
  unsigned u = __builtin_bit_cast(unsigned,f);
  u += 0x7fff + ((u>>16)&1);
  return (ushort)(u>>16);
}

__device__ __forceinline__ int perm_pos(int g, int l){
  switch(g){
    case 0: return l;
    case 1: return ((l & 31) << 5) | (l >> 5);
    case 2: return 1023 - l;
    default:{ int ll = 1023 - l; return ((ll & 31) << 5) | (ll >> 5); }
  }
}

__device__ __forceinline__ void gload16(const void* g, void* l){
  __builtin_amdgcn_global_load_lds((const __attribute__((address_space(1))) void*)g,
                                   (__attribute__((address_space(3))) void*)l, 16, 0, 0);
}

// ---------------- fp32 -> bf16 convert, 3 arrays in one launch ----------------
__global__ __launch_bounds__(256) void k_tobf16_3(
    const float* __restrict__ s1, int n1, ushort* __restrict__ d1,
    const float* __restrict__ s2, int n2, ushort* __restrict__ d2,
    const float* __restrict__ s3, int n3, ushort* __restrict__ d3){
  int i = blockIdx.x*256 + threadIdx.x;
  if (i < n1) d1[i] = f2b(s1[i]);
  else if (i < n1+n2) d2[i-n1] = f2b(s2[i-n1]);
  else if (i < n1+n2+n3) d3[i-n1-n2] = f2b(s3[i-n1-n2]);
}

// ---------------- K1: LayerNorm over C=512, wave-per-token, bf16 out ----------------
__global__ __launch_bounds__(256) void k_ln512(const float* __restrict__ x,
    const float* __restrict__ w, const float* __restrict__ b, ushort* __restrict__ out){
  int wv = threadIdx.x >> 6, lane = threadIdx.x & 63;
  int t = blockIdx.x*4 + wv;
  const float* xr = x + (size_t)t*NC + lane*8;
  float4 a = *(const float4*)xr;
  float4 c = *(const float4*)(xr+4);
  float e[8] = {a.x,a.y,a.z,a.w,c.x,c.y,c.z,c.w};
  float s = 0.f, sq = 0.f;
  #pragma unroll
  for (int i=0;i<8;i++){ s += e[i]; sq += e[i]*e[i]; }
  #pragma unroll
  for (int o=1;o<64;o<<=1){ s += __shfl_xor(s,o); sq += __shfl_xor(sq,o); }
  float m = s*(1.f/NC);
  float var = sq*(1.f/NC) - m*m;
  float rs = rsqrtf(var + 1e-5f);
  const float4* wr = (const float4*)(w + lane*8);
  const float4* br = (const float4*)(b + lane*8);
  float4 w0 = wr[0], w1 = wr[1], b0 = br[0], b1 = br[1];
  float wv8[8] = {w0.x,w0.y,w0.z,w0.w,w1.x,w1.y,w1.z,w1.w};
  float bv8[8] = {b0.x,b0.y,b0.z,b0.w,b1.x,b1.y,b1.z,b1.w};
  bf16x8 o8;
  #pragma unroll
  for (int i=0;i<8;i++) ((ushort*)&o8)[i] = f2b((e[i]-m)*rs*wv8[i]+bv8[i]);
  *(bf16x8*)(out + (size_t)t*NC + lane*8) = o8;
}

// ---------------- K2: column mean, 2-stage ----------------
__global__ __launch_bounds__(512) void k_cm1(const ushort* __restrict__ xn,
    float* __restrict__ part){
  int c = threadIdx.x;
  const ushort* base = xn + ((size_t)blockIdx.x*32)*NC + c;
  float acc = 0.f;
  for (int n=0;n<32;n++) acc += b2f(base[(size_t)n*NC]);
  part[(size_t)blockIdx.x*NC + c] = acc;
}
__global__ __launch_bounds__(512) void k_cm2(const float* __restrict__ part,
    float* __restrict__ zavg){
  int b = blockIdx.x, c = threadIdx.x;
  float acc = 0.f;
  for (int i=0;i<32;i++) acc += part[(size_t)(b*32+i)*NC + c];
  zavg[b*NC+c] = acc * (1.f/1024.f);
}

// ---------------- K3: ECA + FC gate; wave-per-output, coalesced ----------------
__global__ __launch_bounds__(256) void k_gate(const float* __restrict__ zavg,
    const float* __restrict__ fcw, const float* __restrict__ fcb,
    const float* __restrict__ ew, float* __restrict__ gate){
  __shared__ float za[NC];
  int b = blockIdx.x >> 7, og = blockIdx.x & 127;
  int tid = threadIdx.x, lane = tid & 63, wv = tid >> 6;
  za[tid]     = zavg[b*NC + tid];
  za[tid+256] = zavg[b*NC + tid + 256];
  __syncthreads();
  int o = og*4 + wv;
  const float* wr = fcw + (size_t)o*NC;
  float acc = 0.f;
  #pragma unroll
  for (int i=0;i<8;i++) acc += za[lane + i*64]*wr[lane + i*64];
  #pragma unroll
  for (int off=1;off<64;off<<=1) acc += __shfl_xor(acc, off);
  if (lane==0){
    float left  = (o>0)    ? za[o-1] : 0.f;
    float right = (o<NC-1) ? za[o+1] : 0.f;
    float ye = ew[0]*left + ew[1]*za[o] + ew[2]*right;
    gate[b*NC+o] = sigf(acc + fcb[o] + ye);
  }
}

// ---------------- K4: bf16 MFMA GEMM, z-batched ----------------
__global__ __launch_bounds__(256) void k_gemm_bf16(
    const ushort* __restrict__ A, int lda, long sAz,
    const ushort* __restrict__ Bw, int ldb, long sBz, int K,
    ushort* __restrict__ C0, int ldc0, ushort* __restrict__ C1, int ldc1,
    int nsplit, long sCz,
    float* __restrict__ Cf, int ldcf, const float* __restrict__ bias)
{
  __shared__ __align__(16) ushort Asm[128*64];
  __shared__ __align__(16) ushort Bsm[128*64];
  const int z = blockIdx.z;
  A  += (size_t)z*sAz;
  Bw += (size_t)z*sBz;
  if (C0) C0 += (size_t)z*sCz;
  if (C1) C1 += (size_t)z*sCz;
  const int tid = threadIdx.x;
  const int lane = tid & 63, wid = tid >> 6;
  const int wm = wid >> 1, wn = wid & 1;
  const int m0 = blockIdx.y * 128, n0 = blockIdx.x * 128;

  const ushort* ga[4]; const ushort* gb[4]; int ldst[4];
  #pragma unroll
  for (int j=0;j<4;j++){
    int c = tid + 256*j;
    int r = c >> 3;
    int kb = ((c & 7) << 4) ^ ((r & 7) << 4);
    ga[j] = A  + (size_t)(m0 + r)*lda + (kb >> 1);
    gb[j] = Bw + (size_t)(n0 + r)*ldb + (kb >> 1);
    ldst[j] = c * 8;
  }

  f32x4 acc[4][4];
  #pragma unroll
  for (int i=0;i<4;i++)
    #pragma unroll
    for (int j=0;j<4;j++) acc[i][j] = (f32x4){0.f,0.f,0.f,0.f};

  const int lc = lane & 15;
  const int kgrp = (lane >> 4) << 4;

  for (int k0 = 0; k0 < K; k0 += 64){
    #pragma unroll
    for (int j=0;j<4;j++) gload16(ga[j] + k0, Asm + ldst[j]);
    #pragma unroll
    for (int j=0;j<4;j++) gload16(gb[j] + k0, Bsm + ldst[j]);
    __syncthreads();
    #pragma unroll
    for (int kk=0; kk<2; kk++){
      bf16x8 af[4], bfr[4];
      #pragma unroll
      for (int i=0;i<4;i++){
        int ra = wm*64 + i*16 + lc;
        int kb = kk*64 + kgrp;
        af[i] = *(const bf16x8*)((const char*)Asm + ra*128 + (kb ^ ((ra&7)<<4)));
        int rb = wn*64 + i*16 + lc;
        bfr[i] = *(const bf16x8*)((const char*)Bsm + rb*128 + (kb ^ ((rb&7)<<4)));
      }
      #pragma unroll
      for (int i=0;i<4;i++)
        #pragma unroll
        for (int j=0;j<4;j++)
          acc[i][j] = __builtin_amdgcn_mfma_f32_16x16x32_bf16(af[i], bfr[j], acc[i][j], 0, 0, 0);
    }
    __syncthreads();
  }

  const int lr = (lane >> 4) * 4;
  if (Cf){
    #pragma unroll
    for (int i=0;i<4;i++)
      #pragma unroll
      for (int j=0;j<4;j++){
        int row = m0 + wm*64 + i*16 + lr;
        int col = n0 + wn*64 + j*16 + lc;
        float bv = bias ? bias[col] : 0.f;
        #pragma unroll
        for (int r=0;r<4;r++)
          Cf[(size_t)(row+r)*ldcf + col] = acc[i][j][r] + bv;
      }
  } else {
    #pragma unroll
    for (int i=0;i<4;i++)
      #pragma unroll
      for (int j=0;j<4;j++){
        int row = m0 + wm*64 + i*16 + lr;
        int col = n0 + wn*64 + j*16 + lc;
        #pragma unroll
        for (int r=0;r<4;r++){
          ushort hv = f2b(acc[i][j][r]);
          if (col < nsplit) C0[(size_t)(row+r)*ldc0 + col] = hv;
          else              C1[(size_t)(row+r)*ldc1 + col - nsplit] = hv;
        }
      }
  }
}

// ---------------- K5: fused conv3x3+SiLU (wide loads) + x_proj via MFMA ----------------
// block = 64 tokens x 256 thr; thread = (token, 8-d chunk); g = blockIdx.z.
// Writes u (bf16) and xd (12-pad f32).
__global__ __launch_bounds__(256) void k_convxp(const ushort* __restrict__ xc,
    const float* __restrict__ cw, const float* __restrict__ cb,
    const float* __restrict__ xpw, ushort* __restrict__ u, float* __restrict__ xd){
  __shared__ __align__(16) ushort su[64][136];
  int g = blockIdx.z, tid = threadIdx.x;
  int t0 = blockIdx.x * 64;
  int p = tid & 15;           // d-chunk (8 d's)
  int d0 = p*8;

  // weights: this thread's 8 d's x 9 taps = 72 contiguous floats
  float w_[9][8]; float bias[8];
  {
    const float* wk = cw + (size_t)(g*ND + d0)*9;
    #pragma unroll
    for (int j=0;j<8;j++)
      #pragma unroll
      for (int k9=0;k9<9;k9++) w_[k9][j] = wk[j*9+k9];
    const float* cbp = cb + g*ND + d0;
    #pragma unroll
    for (int j=0;j<8;j++) bias[j] = cbp[j];
  }
  const ushort* xcg = xc + (size_t)g*NTOK*ND;

  #pragma unroll
  for (int pass=0; pass<4; pass++){
    int lt = pass*16 + (tid>>4);
    int t = t0 + lt;
    int b = t >> 10, pp = t & 1023, h = pp >> 5, w = pp & 31;
    float acc[8];
    #pragma unroll
    for (int j=0;j<8;j++) acc[j] = bias[j];
    #pragma unroll
    for (int kh=0;kh<3;kh++){
      int hh = h + kh - 1;
      if (hh < 0 || hh >= 32) continue;
      #pragma unroll
      for (int kw=0;kw<3;kw++){
        int w2 = w + kw - 1;
        if (w2 < 0 || w2 >= 32) continue;
        bf16x8 v = *(const bf16x8*)(xcg + (size_t)((b<<10)|(hh<<5)|w2)*ND + d0);
        #pragma unroll
        for (int j=0;j<8;j++) acc[j] = fmaf(b2f(((ushort*)&v)[j]), w_[kh*3+kw][j], acc[j]);
      }
    }
    bf16x8 o8;
    #pragma unroll
    for (int j=0;j<8;j++){
      float uv = acc[j] * sigf(acc[j]);
      ((ushort*)&o8)[j] = f2b(uv);
    }
    *(bf16x8*)(u + ((size_t)g*NTOK + t)*ND + d0) = o8;
    *(bf16x8*)&su[lt][d0] = o8;
  }
  __syncthreads();

  // x_proj: per wave, 16 tokens x 16 outputs (10 real), K=128 via 4 MFMAs
  int lane = tid & 63, wv = tid >> 6;
  int c = lane & 15;
  int kg = (lane >> 4) * 8;
  f32x4 acc4 = (f32x4){0.f,0.f,0.f,0.f};
  const float* xr_base = xpw + (size_t)(g*10 + (c < 10 ? c : 0))*128;
  #pragma unroll
  for (int ks=0; ks<4; ks++){
    bf16x8 af = *(const bf16x8*)&su[wv*16 + (lane & 15)][ks*32 + kg];
    const float* xr = xr_base + ks*32 + kg;
    bf16x8 bfv;
    #pragma unroll
    for (int j=0;j<8;j++) ((ushort*)&bfv)[j] = (c < 10) ? f2b(xr[j]) : (ushort)0;
    acc4 = __builtin_amdgcn_mfma_f32_16x16x32_bf16(af, bfv, acc4, 0, 0, 0);
  }
  if (c < 10){
    #pragma unroll
    for (int r=0;r<4;r++){
      int row = (lane >> 4)*4 + r;
      int t = t0 + wv*16 + row;
      xd[((size_t)g*NTOK + t)*12 + c] = acc4[r];
    }
  }
}

// ---------------- scan helpers ----------------
struct ScanCtx {
  float Ad, dtb_d;
  float w[8];
};

__device__ __forceinline__ void scan_step(const ScanCtx& c, float uv,
    const float4& x0, const float4& x1, float Bv,
    float& h, float& ap){
  float a = c.dtb_d;
  a = fmaf(x0.x, c.w[0], a); a = fmaf(x0.y, c.w[1], a);
  a = fmaf(x0.z, c.w[2], a); a = fmaf(x0.w, c.w[3], a);
  a = fmaf(x1.x, c.w[4], a); a = fmaf(x1.y, c.w[5], a);
  a = fmaf(x1.z, c.w[6], a); a = fmaf(x1.w, c.w[7], a);
  float dl = (a > 20.f) ? a : log1pf(expf(a));
  float av = expf(dl * c.Ad);
  h = fmaf(av, h, dl*Bv*uv);
  ap *= av;
}

// ---------------- K6: scan pass 1 ----------------
__global__ __launch_bounds__(128) void k_scan1(const ushort* __restrict__ u,
    const float* __restrict__ xd, const float* __restrict__ Alog,
    const float* __restrict__ dtw, const float* __restrict__ dtb,
    float* __restrict__ chA, float* __restrict__ chB){
  int d = threadIdx.x, g = blockIdx.z;
  int b = blockIdx.x >> 6, ch = blockIdx.x & 63;
  ScanCtx c;
  c.Ad = -expf(Alog[g*ND+d]);
  c.dtb_d = dtb[g*ND+d];
  const float4* wr = (const float4*)(dtw + (size_t)(g*ND+d)*8);
  float4 w0 = wr[0], w1 = wr[1];
  c.w[0]=w0.x;c.w[1]=w0.y;c.w[2]=w0.z;c.w[3]=w0.w;
  c.w[4]=w1.x;c.w[5]=w1.y;c.w[6]=w1.z;c.w[7]=w1.w;
  float h = 0.f, ap = 1.f;
  int l0 = ch*CST;
  #pragma unroll 4
  for (int s=0;s<CST;s++){
    int pp = perm_pos(g, l0 + s);
    size_t base = (size_t)g*NTOK + ((b<<10)|pp);
    float uv = b2f(u[base*ND + d]);
    const float4* xr = (const float4*)(xd + base*12);
    float4 x0 = xr[0], x1 = xr[1], x2 = xr[2];
    scan_step(c, uv, x0, x1, x2.x, h, ap);
  }
  size_t o = (((size_t)g*16 + b)*NCH + ch)*ND + d;
  chA[o]=ap; chB[o]=h;
}

// ---------------- K7: combine over chunks (full unroll -> load pipelining) ----------------
__global__ __launch_bounds__(128) void k_scomb(const float* __restrict__ chA,
    const float* __restrict__ chB, float* __restrict__ hIn){
  int b = blockIdx.x, g = blockIdx.z, d = threadIdx.x;
  size_t base = (((size_t)g*16 + b)*NCH)*ND + d;
  float hrun = 0.f;
  #pragma unroll
  for (int ch=0; ch<NCH; ch++){
    size_t o = base + (size_t)ch*ND;
    float a = chA[o], bb = chB[o];
    hIn[o] = hrun;
    hrun = fmaf(a, hrun, bb);
  }
}

// ---------------- K8: scan pass 3 ----------------
__global__ __launch_bounds__(128) void k_scan3(const ushort* __restrict__ u,
    const float* __restrict__ xd, const float* __restrict__ Alog,
    const float* __restrict__ dtw, const float* __restrict__ dtb,
    const float* __restrict__ Dp, const float* __restrict__ hIn,
    float* __restrict__ y){
  int d = threadIdx.x, g = blockIdx.z;
  int b = blockIdx.x >> 6, ch = blockIdx.x & 63;
  ScanCtx c;
  c.Ad = -expf(Alog[g*ND+d]);
  c.dtb_d = dtb[g*ND+d];
  float Dd = Dp[g*ND+d];
  const float4* wr = (const float4*)(dtw + (size_t)(g*ND+d)*8);
  float4 w0 = wr[0], w1 = wr[1];
  c.w[0]=w0.x;c.w[1]=w0.y;c.w[2]=w0.z;c.w[3]=w0.w;
  c.w[4]=w1.x;c.w[5]=w1.y;c.w[6]=w1.z;c.w[7]=w1.w;
  float h = hIn[(((size_t)g*16 + b)*NCH + ch)*ND + d];
  float ap = 1.f;
  int l0 = ch*CST;
  #pragma unroll 4
  for (int s=0;s<CST;s++){
    int pp = perm_pos(g, l0 + s);
    size_t base = (size_t)g*NTOK + ((b<<10)|pp);
    float uv = b2f(u[base*ND + d]);
    const float4* xr = (const float4*)(xd + base*12);
    float4 x0 = xr[0], x1 = xr[1], x2 = xr[2];
    scan_step(c, uv, x0, x1, x2.x, h, ap);
    y[base*ND + d] = fmaf(h, x2.y, Dd*uv);
  }
}

// ---------------- K9: out-LN(128) * SiLU(z); 16 tokens/block, 16 lanes/token ----------------
__global__ __launch_bounds__(256) void k_yo(const float* __restrict__ y,
    const ushort* __restrict__ zg, const float* __restrict__ onw,
    const float* __restrict__ onb, ushort* __restrict__ yo){
  int tid = threadIdx.x, g = blockIdx.z;
  int lt = tid >> 4, p = tid & 15;
  int t = blockIdx.x*16 + lt;
  size_t base = ((size_t)g*NTOK + t)*ND + p*8;
  float4 a = *(const float4*)(y + base);
  float4 cc = *(const float4*)(y + base + 4);
  float e[8] = {a.x,a.y,a.z,a.w,cc.x,cc.y,cc.z,cc.w};
  float s = 0.f, sq = 0.f;
  #pragma unroll
  for (int i=0;i<8;i++){ s += e[i]; sq += e[i]*e[i]; }
  #pragma unroll
  for (int o=1;o<16;o<<=1){ s += __shfl_xor(s,o); sq += __shfl_xor(sq,o); }
  float m = s*(1.f/ND);
  float var = sq*(1.f/ND) - m*m;
  float rs = rsqrtf(var + 1e-5f);
  const float4* wr = (const float4*)(onw + g*ND + p*8);
  const float4* br = (const float4*)(onb + g*ND + p*8);
  float4 w0 = wr[0], w1 = wr[1], b0 = br[0], b1 = br[1];
  float wv8[8] = {w0.x,w0.y,w0.z,w0.w,w1.x,w1.y,w1.z,w1.w};
  float bv8[8] = {b0.x,b0.y,b0.z,b0.w,b1.x,b1.y,b1.z,b1.w};
  bf16x8 zv = *(const bf16x8*)(zg + base);
  bf16x8 o8;
  #pragma unroll
  for (int i=0;i<8;i++){
    float yn = (e[i]-m)*rs*wv8[i]+bv8[i];
    float z = b2f(((ushort*)&zv)[i]);
    ((ushort*)&o8)[i] = f2b(yn * z * sigf(z));
  }
  *(bf16x8*)(yo + base) = o8;
}

// ---------------- K10: skip*xh*gate then LN(512); wave-per-token ----------------
__global__ __launch_bounds__(256) void k_gateln(const ushort* __restrict__ ybuf,
    const ushort* __restrict__ xn, const float* __restrict__ gate,
    const float* __restrict__ skip, const float* __restrict__ w,
    const float* __restrict__ b, ushort* __restrict__ out){
  int wv = threadIdx.x >> 6, lane = threadIdx.x & 63;
  int t = blockIdx.x*4 + wv, bb = t >> 10;
  float ss = skip[0];
  size_t o0 = (size_t)t*NC + lane*8;
  bf16x8 yv = *(const bf16x8*)(ybuf + o0);
  bf16x8 xv = *(const bf16x8*)(xn + o0);
  const float4* gr = (const float4*)(gate + bb*NC + lane*8);
  float4 g0 = gr[0], g1 = gr[1];
  float gv8[8] = {g0.x,g0.y,g0.z,g0.w,g1.x,g1.y,g1.z,g1.w};
  float e[8];
  float s = 0.f, sq = 0.f;
  #pragma unroll
  for (int i=0;i<8;i++){
    e[i] = b2f(((ushort*)&yv)[i]) * ss * b2f(((ushort*)&xv)[i]) * gv8[i];
    s += e[i]; sq += e[i]*e[i];
  }
  #pragma unroll
  for (int o=1;o<64;o<<=1){ s += __shfl_xor(s,o); sq += __shfl_xor(sq,o); }
  float m = s*(1.f/NC);
  float var = sq*(1.f/NC) - m*m;
  float rs = rsqrtf(var + 1e-5f);
  const float4* wr = (const float4*)(w + lane*8);
  const float4* br = (const float4*)(b + lane*8);
  float4 w0 = wr[0], w1 = wr[1], b0 = br[0], b1 = br[1];
  float wv8[8] = {w0.x,w0.y,w0.z,w0.w,w1.x,w1.y,w1.z,w1.w};
  float bv8[8] = {b0.x,b0.y,b0.z,b0.w,b1.x,b1.y,b1.z,b1.w};
  bf16x8 o8;
  #pragma unroll
  for (int i=0;i<8;i++) ((ushort*)&o8)[i] = f2b((e[i]-m)*rs*wv8[i]+bv8[i]);
  *(bf16x8*)(out + o0) = o8;
}

extern "C" void kernel_launch(void* const* d_in, const int* in_sizes, int n_in,
                              void* d_out, int out_size, void* d_ws, size_t ws_size,
                              hipStream_t stream) {
  const float* x          = (const float*)d_in[0];
  const float* norm_w     = (const float*)d_in[3];
  const float* norm_b     = (const float*)d_in[4];
  const float* fc_w       = (const float*)d_in[5];
  const float* fc_b       = (const float*)d_in[6];
  const float* eca_w      = (const float*)d_in[7];
  const float* skip_scale = (const float*)d_in[8];
  const float* proj_w     = (const float*)d_in[9];
  const float* proj_b     = (const float*)d_in[10];
  const float* in_proj_w  = (const float*)d_in[11];
  const float* conv_w     = (const float*)d_in[12];
  const float* conv_b     = (const float*)d_in[13];
  const float* x_proj_w   = (const float*)d_in[14];
  const float* dt_proj_w  = (const float*)d_in[15];
  const float* dt_proj_b  = (const float*)d_in[16];
  const float* A_log      = (const float*)d_in[17];
  const float* D_param    = (const float*)d_in[18];
  const float* out_norm_w = (const float*)d_in[19];
  const float* out_norm_b = (const float*)d_in[20];
  const float* out_proj_w = (const float*)d_in[21];
  float* out = (float*)d_out;
  float* ws  = (float*)d_ws;

  // ---- workspace layout (float units) ----
  ushort* xn_b   = (ushort*)(ws);                  // 16384*512 bf16
  ushort* ybuf_b = (ushort*)(ws + 4194304);
  ushort* xc4    = (ushort*)(ws + 8388608);        // 4*16384*128 bf16
  ushort* zg4    = (ushort*)(ws + 12582912);
  ushort* yo4    = (ushort*)(ws + 16777216);
  ushort* u4b    = (ushort*)(ws + 20971520);       // 4*16384*128 bf16
  float*  y4     = ws + 25165824;                  // 4*16384*128 f32
  float*  xd4    = ws + 33554432;                  // 4*16384*12 f32
  float*  chA    = ws + 34340864;                  // 4*16*64*128
  float*  chB    = ws + 34865152;
  float*  hIn    = ws + 35389440;
  float*  zavg   = ws + 35913728;
  float*  gatep  = ws + 35921920;
  float*  part   = ws + 35930112;
  ushort* wb_in  = (ushort*)(ws + 36192256);
  ushort* wb_out = (ushort*)(ws + 36257792);
  ushort* wb_prj = (ushort*)(ws + 36290560);
  ushort* xmn_b  = (ushort*)(ws + 36421632);

  k_ln512<<<dim3(NTOK/4), dim3(256), 0, stream>>>(x, norm_w, norm_b, xn_b);
  k_cm1<<<dim3(512), dim3(512), 0, stream>>>(xn_b, part);
  k_cm2<<<dim3(16), dim3(512), 0, stream>>>(part, zavg);
  k_gate<<<dim3(16*128), dim3(256), 0, stream>>>(zavg, fc_w, fc_b, eca_w, gatep);
  k_tobf16_3<<<dim3(1792), dim3(256), 0, stream>>>(
      in_proj_w, 131072, wb_in, out_proj_w, 65536, wb_out, proj_w, 262144, wb_prj);

  // in_proj (batched over g)
  k_gemm_bf16<<<dim3(2,128,4), dim3(256), 0, stream>>>(
      xn_b, NC, 128, wb_in, 128, 256*128, 128,
      xc4, 128, zg4, 128, 128, (long)NTOK*128,
      (float*)nullptr, 0, (const float*)nullptr);

  k_convxp<<<dim3(NTOK/64,1,4), dim3(256), 0, stream>>>(
      xc4, conv_w, conv_b, x_proj_w, u4b, xd4);

  k_scan1<<<dim3(16*NCH,1,4), dim3(128), 0, stream>>>(
      u4b, xd4, A_log, dt_proj_w, dt_proj_b, chA, chB);
  k_scomb<<<dim3(16,1,4), dim3(128), 0, stream>>>(chA, chB, hIn);
  k_scan3<<<dim3(16*NCH,1,4), dim3(128), 0, stream>>>(
      u4b, xd4, A_log, dt_proj_w, dt_proj_b, D_param, hIn, y4);

  k_yo<<<dim3(NTOK/16,1,4), dim3(256), 0, stream>>>(
      y4, zg4, out_norm_w, out_norm_b, yo4);

  // out_proj (batched)
  k_gemm_bf16<<<dim3(1,128,4), dim3(256), 0, stream>>>(
      yo4, 128, (long)NTOK*128, wb_out, 128, 128*128, 128,
      ybuf_b, NC, ybuf_b, NC, 1<<30, 128,
      (float*)nullptr, 0, (const float*)nullptr);

  k_gateln<<<dim3(NTOK/4), dim3(256), 0, stream>>>(
      ybuf_b, xn_b, gatep, skip_scale, norm_w, norm_b, xmn_b);

  // final proj -> out (fp32)
  k_gemm_bf16<<<dim3(4,128,1), dim3(256), 0, stream>>>(
      xmn_b, NC, 0, wb_prj, NC, 0, NC,
      (ushort*)nullptr, 0, (ushort*)nullptr, 0, 0, 0,
      out, NC, proj_b);
}

// Round 7
// 183.615 us; speedup vs baseline: 4.7206x; 1.1060x over previous
//
#include <hip/hip_runtime.h>
#include <math.h>

// B=16, H=W=32, C=512, D=128/group, S=1, R=8
#define NTOK 16384
#define NC 512
#define ND 128
#define NCH 64   // scan chunks per (b,g)
#define CST 16   // steps per chunk

typedef __attribute__((ext_vector_type(8))) short bf16x8;
typedef __attribute__((ext_vector_type(4))) float f32x4;

__device__ __forceinline__ float sigf(float x){ return 1.f/(1.f+expf(-x)); }
__device__ __forceinline__ float b2f(ushort u){ unsigned x = ((unsigned)u)<<16; return __builtin_bit_cast(float,x); }
__device__ __forceinline__ ushort f2b(float f){
  unsigned u = __builtin_bit_cast(unsigned,f);
  u += 0x7fff + ((u>>16)&1);
  return (ushort)(u>>16);
}

__device__ __forceinline__ int perm_pos(int g, int l){
  switch(g){
    case 0: return l;
    case 1: return ((l & 31) << 5) | (l >> 5);
    case 2: return 1023 - l;
    default:{ int ll = 1023 - l; return ((ll & 31) << 5) | (ll >> 5); }
  }
}

__device__ __forceinline__ void gload16(const void* g, void* l){
  __builtin_amdgcn_global_load_lds((const __attribute__((address_space(1))) void*)g,
                                   (__attribute__((address_space(3))) void*)l, 16, 0, 0);
}

// ---------------- fp32 -> bf16 convert, 4 arrays in one launch ----------------
__global__ __launch_bounds__(256) void k_tobf16_4(
    const float* __restrict__ s1, int n1, ushort* __restrict__ d1,
    const float* __restrict__ s2, int n2, ushort* __restrict__ d2,
    const float* __restrict__ s3, int n3, ushort* __restrict__ d3,
    const float* __restrict__ s4, int n4, ushort* __restrict__ d4){
  int i = blockIdx.x*256 + threadIdx.x;
  if (i < n1) d1[i] = f2b(s1[i]);
  else if (i < n1+n2) d2[i-n1] = f2b(s2[i-n1]);
  else if (i < n1+n2+n3) d3[i-n1-n2] = f2b(s3[i-n1-n2]);
  else if (i < n1+n2+n3+n4) d4[i-n1-n2-n3] = f2b(s4[i-n1-n2-n3]);
}

// ---------------- K1: LayerNorm over C=512, wave-per-token, bf16 out ----------------
__global__ __launch_bounds__(256) void k_ln512(const float* __restrict__ x,
    const float* __restrict__ w, const float* __restrict__ b, ushort* __restrict__ out){
  int wv = threadIdx.x >> 6, lane = threadIdx.x & 63;
  int t = blockIdx.x*4 + wv;
  const float* xr = x + (size_t)t*NC + lane*8;
  float4 a = *(const float4*)xr;
  float4 c = *(const float4*)(xr+4);
  float e[8] = {a.x,a.y,a.z,a.w,c.x,c.y,c.z,c.w};
  float s = 0.f, sq = 0.f;
  #pragma unroll
  for (int i=0;i<8;i++){ s += e[i]; sq += e[i]*e[i]; }
  #pragma unroll
  for (int o=1;o<64;o<<=1){ s += __shfl_xor(s,o); sq += __shfl_xor(sq,o); }
  float m = s*(1.f/NC);
  float var = sq*(1.f/NC) - m*m;
  float rs = rsqrtf(var + 1e-5f);
  const float4* wr = (const float4*)(w + lane*8);
  const float4* br = (const float4*)(b + lane*8);
  float4 w0 = wr[0], w1 = wr[1], b0 = br[0], b1 = br[1];
  float wv8[8] = {w0.x,w0.y,w0.z,w0.w,w1.x,w1.y,w1.z,w1.w};
  float bv8[8] = {b0.x,b0.y,b0.z,b0.w,b1.x,b1.y,b1.z,b1.w};
  bf16x8 o8;
  #pragma unroll
  for (int i=0;i<8;i++) ((ushort*)&o8)[i] = f2b((e[i]-m)*rs*wv8[i]+bv8[i]);
  *(bf16x8*)(out + (size_t)t*NC + lane*8) = o8;
}

// ---------------- K2: column mean, 2-stage ----------------
__global__ __launch_bounds__(512) void k_cm1(const ushort* __restrict__ xn,
    float* __restrict__ part){
  int c = threadIdx.x;
  const ushort* base = xn + ((size_t)blockIdx.x*32)*NC + c;
  float acc = 0.f;
  for (int n=0;n<32;n++) acc += b2f(base[(size_t)n*NC]);
  part[(size_t)blockIdx.x*NC + c] = acc;
}
__global__ __launch_bounds__(512) void k_cm2(const float* __restrict__ part,
    float* __restrict__ zavg){
  int b = blockIdx.x, c = threadIdx.x;
  float acc = 0.f;
  for (int i=0;i<32;i++) acc += part[(size_t)(b*32+i)*NC + c];
  zavg[b*NC+c] = acc * (1.f/1024.f);
}

// ---------------- K3: ECA + FC gate; wave-per-output, coalesced ----------------
__global__ __launch_bounds__(256) void k_gate(const float* __restrict__ zavg,
    const float* __restrict__ fcw, const float* __restrict__ fcb,
    const float* __restrict__ ew, float* __restrict__ gate){
  __shared__ float za[NC];
  int b = blockIdx.x >> 7, og = blockIdx.x & 127;
  int tid = threadIdx.x, lane = tid & 63, wv = tid >> 6;
  za[tid]     = zavg[b*NC + tid];
  za[tid+256] = zavg[b*NC + tid + 256];
  __syncthreads();
  int o = og*4 + wv;
  const float* wr = fcw + (size_t)o*NC;
  float acc = 0.f;
  #pragma unroll
  for (int i=0;i<8;i++) acc += za[lane + i*64]*wr[lane + i*64];
  #pragma unroll
  for (int off=1;off<64;off<<=1) acc += __shfl_xor(acc, off);
  if (lane==0){
    float left  = (o>0)    ? za[o-1] : 0.f;
    float right = (o<NC-1) ? za[o+1] : 0.f;
    float ye = ew[0]*left + ew[1]*za[o] + ew[2]*right;
    gate[b*NC+o] = sigf(acc + fcb[o] + ye);
  }
}

// ---------------- K4: bf16 MFMA GEMM, z-batched ----------------
__global__ __launch_bounds__(256) void k_gemm_bf16(
    const ushort* __restrict__ A, int lda, long sAz,
    const ushort* __restrict__ Bw, int ldb, long sBz, int K,
    ushort* __restrict__ C0, int ldc0, ushort* __restrict__ C1, int ldc1,
    int nsplit, long sCz,
    float* __restrict__ Cf, int ldcf, const float* __restrict__ bias)
{
  __shared__ __align__(16) ushort Asm[128*64];
  __shared__ __align__(16) ushort Bsm[128*64];
  const int z = blockIdx.z;
  A  += (size_t)z*sAz;
  Bw += (size_t)z*sBz;
  if (C0) C0 += (size_t)z*sCz;
  if (C1) C1 += (size_t)z*sCz;
  const int tid = threadIdx.x;
  const int lane = tid & 63, wid = tid >> 6;
  const int wm = wid >> 1, wn = wid & 1;
  const int m0 = blockIdx.y * 128, n0 = blockIdx.x * 128;

  const ushort* ga[4]; const ushort* gb[4]; int ldst[4];
  #pragma unroll
  for (int j=0;j<4;j++){
    int c = tid + 256*j;
    int r = c >> 3;
    int kb = ((c & 7) << 4) ^ ((r & 7) << 4);
    ga[j] = A  + (size_t)(m0 + r)*lda + (kb >> 1);
    gb[j] = Bw + (size_t)(n0 + r)*ldb + (kb >> 1);
    ldst[j] = c * 8;
  }

  f32x4 acc[4][4];
  #pragma unroll
  for (int i=0;i<4;i++)
    #pragma unroll
    for (int j=0;j<4;j++) acc[i][j] = (f32x4){0.f,0.f,0.f,0.f};

  const int lc = lane & 15;
  const int kgrp = (lane >> 4) << 4;

  for (int k0 = 0; k0 < K; k0 += 64){
    #pragma unroll
    for (int j=0;j<4;j++) gload16(ga[j] + k0, Asm + ldst[j]);
    #pragma unroll
    for (int j=0;j<4;j++) gload16(gb[j] + k0, Bsm + ldst[j]);
    __syncthreads();
    #pragma unroll
    for (int kk=0; kk<2; kk++){
      bf16x8 af[4], bfr[4];
      #pragma unroll
      for (int i=0;i<4;i++){
        int ra = wm*64 + i*16 + lc;
        int kb = kk*64 + kgrp;
        af[i] = *(const bf16x8*)((const char*)Asm + ra*128 + (kb ^ ((ra&7)<<4)));
        int rb = wn*64 + i*16 + lc;
        bfr[i] = *(const bf16x8*)((const char*)Bsm + rb*128 + (kb ^ ((rb&7)<<4)));
      }
      #pragma unroll
      for (int i=0;i<4;i++)
        #pragma unroll
        for (int j=0;j<4;j++)
          acc[i][j] = __builtin_amdgcn_mfma_f32_16x16x32_bf16(af[i], bfr[j], acc[i][j], 0, 0, 0);
    }
    __syncthreads();
  }

  const int lr = (lane >> 4) * 4;
  if (Cf){
    #pragma unroll
    for (int i=0;i<4;i++)
      #pragma unroll
      for (int j=0;j<4;j++){
        int row = m0 + wm*64 + i*16 + lr;
        int col = n0 + wn*64 + j*16 + lc;
        float bv = bias ? bias[col] : 0.f;
        #pragma unroll
        for (int r=0;r<4;r++)
          Cf[(size_t)(row+r)*ldcf + col] = acc[i][j][r] + bv;
      }
  } else {
    #pragma unroll
    for (int i=0;i<4;i++)
      #pragma unroll
      for (int j=0;j<4;j++){
        int row = m0 + wm*64 + i*16 + lr;
        int col = n0 + wn*64 + j*16 + lc;
        #pragma unroll
        for (int r=0;r<4;r++){
          ushort hv = f2b(acc[i][j][r]);
          if (col < nsplit) C0[(size_t)(row+r)*ldc0 + col] = hv;
          else              C1[(size_t)(row+r)*ldc1 + col - nsplit] = hv;
        }
      }
  }
}

// ---------------- K5: conv3x3+SiLU from LDS-staged halo + x_proj via MFMA ----------------
__global__ __launch_bounds__(256) void k_convxp(const ushort* __restrict__ xc,
    const float* __restrict__ cw, const float* __restrict__ cb,
    const ushort* __restrict__ xpw_b, ushort* __restrict__ u, float* __restrict__ xd){
  __shared__ __align__(16) ushort xin[4*32*128];   // 32 KB halo window
  __shared__ __align__(16) ushort su[64][136];     // conv output for x_proj
  int g = blockIdx.z, tid = threadIdx.x;
  int blk = blockIdx.x;
  int bimg = blk >> 4, rp = blk & 15;
  int t0 = blk * 64;
  const ushort* xcg = xc + (size_t)g*NTOK*ND;

  // ---- stage 4 rows x 32 w x 128 d (2048 x 16B chunks, 8 per thread) ----
  #pragma unroll
  for (int j=0;j<8;j++){
    int c = tid + 256*j;          // 0..2047
    int r = c >> 9;               // local row 0..3
    int rest = c & 511;
    int gr = 2*rp + r - 1;
    gr = min(max(gr, 0), 31);     // clamp; invalid rows never read by conv
    int w = rest >> 4, p = rest & 15;
    gload16(xcg + ((size_t)((bimg<<10) | (gr<<5) | w))*ND + p*8, (ushort*)xin + c*8);
  }

  int p = tid & 15, d0 = p*8;
  float w_[9][8]; float bias[8];
  {
    const float* wk = cw + (size_t)(g*ND + d0)*9;
    #pragma unroll
    for (int j=0;j<8;j++)
      #pragma unroll
      for (int k9=0;k9<9;k9++) w_[k9][j] = wk[j*9+k9];
    const float* cbp = cb + g*ND + d0;
    #pragma unroll
    for (int j=0;j<8;j++) bias[j] = cbp[j];
  }
  __syncthreads();

  #pragma unroll
  for (int pass=0; pass<4; pass++){
    int lt = pass*16 + (tid>>4);
    int hl = lt >> 5, w = lt & 31;    // hl uniform per pass
    int t = t0 + lt;
    float acc[8];
    #pragma unroll
    for (int j=0;j<8;j++) acc[j] = bias[j];
    #pragma unroll
    for (int kh=0;kh<3;kh++){
      int gr = 2*rp + hl + kh - 1;
      if (gr < 0 || gr >= 32) continue;      // block-uniform skip
      #pragma unroll
      for (int kw=0;kw<3;kw++){
        int w2 = w + kw - 1;
        if (w2 < 0 || w2 >= 32) continue;    // edge-lane predication
        bf16x8 v = *(const bf16x8*)&xin[((hl+kh)*32 + w2)*128 + d0];
        #pragma unroll
        for (int j=0;j<8;j++) acc[j] = fmaf(b2f(((ushort*)&v)[j]), w_[kh*3+kw][j], acc[j]);
      }
    }
    bf16x8 o8;
    #pragma unroll
    for (int j=0;j<8;j++){
      float uv = acc[j] * sigf(acc[j]);
      ((ushort*)&o8)[j] = f2b(uv);
    }
    *(bf16x8*)(u + ((size_t)g*NTOK + t)*ND + d0) = o8;
    *(bf16x8*)&su[lt][d0] = o8;
  }
  __syncthreads();

  // x_proj: per wave, 16 tokens x 16 outputs (10 real), K=128 via 4 MFMAs
  int lane = tid & 63, wv = tid >> 6;
  int c = lane & 15;
  int kg = (lane >> 4) * 8;
  int cc = c < 10 ? c : 0;
  f32x4 acc4 = (f32x4){0.f,0.f,0.f,0.f};
  #pragma unroll
  for (int ks=0; ks<4; ks++){
    bf16x8 af = *(const bf16x8*)&su[wv*16 + (lane & 15)][ks*32 + kg];
    bf16x8 bfv = *(const bf16x8*)(xpw_b + (size_t)(g*10+cc)*128 + ks*32 + kg);
    if (c >= 10) bfv = (bf16x8){0,0,0,0,0,0,0,0};
    acc4 = __builtin_amdgcn_mfma_f32_16x16x32_bf16(af, bfv, acc4, 0, 0, 0);
  }
  if (c < 10){
    #pragma unroll
    for (int r=0;r<4;r++){
      int row = (lane >> 4)*4 + r;
      int t = t0 + wv*16 + row;
      xd[((size_t)g*NTOK + t)*12 + c] = acc4[r];
    }
  }
}

// ---------------- scan helpers ----------------
struct ScanCtx {
  float Ad, dtb_d;
  float w[8];
};

__device__ __forceinline__ void scan_step(const ScanCtx& c, float uv,
    const float4& x0, const float4& x1, float Bv,
    float& h, float& ap){
  float a = c.dtb_d;
  a = fmaf(x0.x, c.w[0], a); a = fmaf(x0.y, c.w[1], a);
  a = fmaf(x0.z, c.w[2], a); a = fmaf(x0.w, c.w[3], a);
  a = fmaf(x1.x, c.w[4], a); a = fmaf(x1.y, c.w[5], a);
  a = fmaf(x1.z, c.w[6], a); a = fmaf(x1.w, c.w[7], a);
  float dl = (a > 20.f) ? a : log1pf(expf(a));
  float av = expf(dl * c.Ad);
  h = fmaf(av, h, dl*Bv*uv);
  ap *= av;
}

// ---------------- K6: scan pass 1 ----------------
__global__ __launch_bounds__(128) void k_scan1(const ushort* __restrict__ u,
    const float* __restrict__ xd, const float* __restrict__ Alog,
    const float* __restrict__ dtw, const float* __restrict__ dtb,
    float* __restrict__ chA, float* __restrict__ chB){
  int d = threadIdx.x, g = blockIdx.z;
  int b = blockIdx.x >> 6, ch = blockIdx.x & 63;
  ScanCtx c;
  c.Ad = -expf(Alog[g*ND+d]);
  c.dtb_d = dtb[g*ND+d];
  const float4* wr = (const float4*)(dtw + (size_t)(g*ND+d)*8);
  float4 w0 = wr[0], w1 = wr[1];
  c.w[0]=w0.x;c.w[1]=w0.y;c.w[2]=w0.z;c.w[3]=w0.w;
  c.w[4]=w1.x;c.w[5]=w1.y;c.w[6]=w1.z;c.w[7]=w1.w;
  float h = 0.f, ap = 1.f;
  int l0 = ch*CST;
  #pragma unroll 4
  for (int s=0;s<CST;s++){
    int pp = perm_pos(g, l0 + s);
    size_t base = (size_t)g*NTOK + ((b<<10)|pp);
    float uv = b2f(u[base*ND + d]);
    const float4* xr = (const float4*)(xd + base*12);
    float4 x0 = xr[0], x1 = xr[1], x2 = xr[2];
    scan_step(c, uv, x0, x1, x2.x, h, ap);
  }
  size_t o = (((size_t)g*16 + b)*NCH + ch)*ND + d;
  chA[o]=ap; chB[o]=h;
}

// ---------------- K7: combine over chunks ----------------
__global__ __launch_bounds__(128) void k_scomb(const float* __restrict__ chA,
    const float* __restrict__ chB, float* __restrict__ hIn){
  int b = blockIdx.x, g = blockIdx.z, d = threadIdx.x;
  size_t base = (((size_t)g*16 + b)*NCH)*ND + d;
  float hrun = 0.f;
  #pragma unroll
  for (int ch=0; ch<NCH; ch++){
    size_t o = base + (size_t)ch*ND;
    float a = chA[o], bb = chB[o];
    hIn[o] = hrun;
    hrun = fmaf(a, hrun, bb);
  }
}

// ---------------- K8: scan pass 3 (bf16 y out) ----------------
__global__ __launch_bounds__(128) void k_scan3(const ushort* __restrict__ u,
    const float* __restrict__ xd, const float* __restrict__ Alog,
    const float* __restrict__ dtw, const float* __restrict__ dtb,
    const float* __restrict__ Dp, const float* __restrict__ hIn,
    ushort* __restrict__ y){
  int d = threadIdx.x, g = blockIdx.z;
  int b = blockIdx.x >> 6, ch = blockIdx.x & 63;
  ScanCtx c;
  c.Ad = -expf(Alog[g*ND+d]);
  c.dtb_d = dtb[g*ND+d];
  float Dd = Dp[g*ND+d];
  const float4* wr = (const float4*)(dtw + (size_t)(g*ND+d)*8);
  float4 w0 = wr[0], w1 = wr[1];
  c.w[0]=w0.x;c.w[1]=w0.y;c.w[2]=w0.z;c.w[3]=w0.w;
  c.w[4]=w1.x;c.w[5]=w1.y;c.w[6]=w1.z;c.w[7]=w1.w;
  float h = hIn[(((size_t)g*16 + b)*NCH + ch)*ND + d];
  float ap = 1.f;
  int l0 = ch*CST;
  #pragma unroll 4
  for (int s=0;s<CST;s++){
    int pp = perm_pos(g, l0 + s);
    size_t base = (size_t)g*NTOK + ((b<<10)|pp);
    float uv = b2f(u[base*ND + d]);
    const float4* xr = (const float4*)(xd + base*12);
    float4 x0 = xr[0], x1 = xr[1], x2 = xr[2];
    scan_step(c, uv, x0, x1, x2.x, h, ap);
    y[base*ND + d] = f2b(fmaf(h, x2.y, Dd*uv));
  }
}

// ---------------- K9: out-LN(128) * SiLU(z); bf16 in/out ----------------
__global__ __launch_bounds__(256) void k_yo(const ushort* __restrict__ y,
    const ushort* __restrict__ zg, const float* __restrict__ onw,
    const float* __restrict__ onb, ushort* __restrict__ yo){
  int tid = threadIdx.x, g = blockIdx.z;
  int lt = tid >> 4, p = tid & 15;
  int t = blockIdx.x*16 + lt;
  size_t base = ((size_t)g*NTOK + t)*ND + p*8;
  bf16x8 yv8 = *(const bf16x8*)(y + base);
  float e[8];
  float s = 0.f, sq = 0.f;
  #pragma unroll
  for (int i=0;i<8;i++){
    e[i] = b2f(((ushort*)&yv8)[i]);
    s += e[i]; sq += e[i]*e[i];
  }
  #pragma unroll
  for (int o=1;o<16;o<<=1){ s += __shfl_xor(s,o); sq += __shfl_xor(sq,o); }
  float m = s*(1.f/ND);
  float var = sq*(1.f/ND) - m*m;
  float rs = rsqrtf(var + 1e-5f);
  const float4* wr = (const float4*)(onw + g*ND + p*8);
  const float4* br = (const float4*)(onb + g*ND + p*8);
  float4 w0 = wr[0], w1 = wr[1], b0 = br[0], b1 = br[1];
  float wv8[8] = {w0.x,w0.y,w0.z,w0.w,w1.x,w1.y,w1.z,w1.w};
  float bv8[8] = {b0.x,b0.y,b0.z,b0.w,b1.x,b1.y,b1.z,b1.w};
  bf16x8 zv = *(const bf16x8*)(zg + base);
  bf16x8 o8;
  #pragma unroll
  for (int i=0;i<8;i++){
    float yn = (e[i]-m)*rs*wv8[i]+bv8[i];
    float z = b2f(((ushort*)&zv)[i]);
    ((ushort*)&o8)[i] = f2b(yn * z * sigf(z));
  }
  *(bf16x8*)(yo + base) = o8;
}

// ---------------- K10: skip*xh*gate then LN(512); wave-per-token ----------------
__global__ __launch_bounds__(256) void k_gateln(const ushort* __restrict__ ybuf,
    const ushort* __restrict__ xn, const float* __restrict__ gate,
    const float* __restrict__ skip, const float* __restrict__ w,
    const float* __restrict__ b, ushort* __restrict__ out){
  int wv = threadIdx.x >> 6, lane = threadIdx.x & 63;
  int t = blockIdx.x*4 + wv, bb = t >> 10;
  float ss = skip[0];
  size_t o0 = (size_t)t*NC + lane*8;
  bf16x8 yv = *(const bf16x8*)(ybuf + o0);
  bf16x8 xv = *(const bf16x8*)(xn + o0);
  const float4* gr = (const float4*)(gate + bb*NC + lane*8);
  float4 g0 = gr[0], g1 = gr[1];
  float gv8[8] = {g0.x,g0.y,g0.z,g0.w,g1.x,g1.y,g1.z,g1.w};
  float e[8];
  float s = 0.f, sq = 0.f;
  #pragma unroll
  for (int i=0;i<8;i++){
    e[i] = b2f(((ushort*)&yv)[i]) * ss * b2f(((ushort*)&xv)[i]) * gv8[i];
    s += e[i]; sq += e[i]*e[i];
  }
  #pragma unroll
  for (int o=1;o<64;o<<=1){ s += __shfl_xor(s,o); sq += __shfl_xor(sq,o); }
  float m = s*(1.f/NC);
  float var = sq*(1.f/NC) - m*m;
  float rs = rsqrtf(var + 1e-5f);
  const float4* wr = (const float4*)(w + lane*8);
  const float4* br = (const float4*)(b + lane*8);
  float4 w0 = wr[0], w1 = wr[1], b0 = br[0], b1 = br[1];
  float wv8[8] = {w0.x,w0.y,w0.z,w0.w,w1.x,w1.y,w1.z,w1.w};
  float bv8[8] = {b0.x,b0.y,b0.z,b0.w,b1.x,b1.y,b1.z,b1.w};
  bf16x8 o8;
  #pragma unroll
  for (int i=0;i<8;i++) ((ushort*)&o8)[i] = f2b((e[i]-m)*rs*wv8[i]+bv8[i]);
  *(bf16x8*)(out + o0) = o8;
}

extern "C" void kernel_launch(void* const* d_in, const int* in_sizes, int n_in,
                              void* d_out, int out_size, void* d_ws, size_t ws_size,
                              hipStream_t stream) {
  const float* x          = (const float*)d_in[0];
  const float* norm_w     = (const float*)d_in[3];
  const float* norm_b     = (const float*)d_in[4];
  const float* fc_w       = (const float*)d_in[5];
  const float* fc_b       = (const float*)d_in[6];
  const float* eca_w      = (const float*)d_in[7];
  const float* skip_scale = (const float*)d_in[8];
  const float* proj_w     = (const float*)d_in[9];
  const float* proj_b     = (const float*)d_in[10];
  const float* in_proj_w  = (const float*)d_in[11];
  const float* conv_w     = (const float*)d_in[12];
  const float* conv_b     = (const float*)d_in[13];
  const float* x_proj_w   = (const float*)d_in[14];
  const float* dt_proj_w  = (const float*)d_in[15];
  const float* dt_proj_b  = (const float*)d_in[16];
  const float* A_log      = (const float*)d_in[17];
  const float* D_param    = (const float*)d_in[18];
  const float* out_norm_w = (const float*)d_in[19];
  const float* out_norm_b = (const float*)d_in[20];
  const float* out_proj_w = (const float*)d_in[21];
  float* out = (float*)d_out;
  float* ws  = (float*)d_ws;

  // ---- workspace layout (float units) — sizes verified disjoint:
  // bf16 buffer of N elems occupies N/2 floats.
  ushort* xn_b   = (ushort*)(ws);                  // [0,        4194304)  16384*512 bf16
  ushort* ybuf_b = (ushort*)(ws + 4194304);        // [4194304,  8388608)
  ushort* xc4    = (ushort*)(ws + 8388608);        // [8388608, 12582912)  4*16384*128 bf16
  ushort* zg4    = (ushort*)(ws + 12582912);       // [12582912,16777216)
  ushort* yo4    = (ushort*)(ws + 16777216);       // [16777216,20971520)
  ushort* u4b    = (ushort*)(ws + 20971520);       // [20971520,25165824)  4*16384*128 bf16
  ushort* y4b    = (ushort*)(ws + 25165824);       // [25165824,29360128)  4*16384*128 bf16
  float*  xd4    = ws + 29360128;                  // [29360128,30146560)  4*16384*12 f32
  float*  chA    = ws + 30146560;                  // [30146560,30670848)  4*16*64*128
  float*  chB    = ws + 30670848;                  // [30670848,31195136)
  float*  hIn    = ws + 31195136;                  // [31195136,31719424)
  float*  zavg   = ws + 31719424;                  // +8192
  float*  gatep  = ws + 31727616;                  // +8192
  float*  part   = ws + 31735808;                  // +262144 -> 31997952
  ushort* wb_in  = (ushort*)(ws + 31997952);       // 131072 bf16 = 65536 fl
  ushort* wb_out = (ushort*)(ws + 32063488);       // 65536 bf16 = 32768 fl
  ushort* wb_prj = (ushort*)(ws + 32096256);       // 262144 bf16 = 131072 fl
  ushort* wb_xp  = (ushort*)(ws + 32227328);       // 5120 bf16 = 2560 fl
  ushort* xmn_b  = (ushort*)(ws + 32229888);       // [32229888,36424192) 16384*512 bf16
  // end: 36424192 floats = 145.7 MB

  k_ln512<<<dim3(NTOK/4), dim3(256), 0, stream>>>(x, norm_w, norm_b, xn_b);
  k_cm1<<<dim3(512), dim3(512), 0, stream>>>(xn_b, part);
  k_cm2<<<dim3(16), dim3(512), 0, stream>>>(part, zavg);
  k_gate<<<dim3(16*128), dim3(256), 0, stream>>>(zavg, fc_w, fc_b, eca_w, gatep);
  k_tobf16_4<<<dim3(1812), dim3(256), 0, stream>>>(
      in_proj_w, 131072, wb_in, out_proj_w, 65536, wb_out,
      proj_w, 262144, wb_prj, x_proj_w, 5120, wb_xp);

  // in_proj (batched over g)
  k_gemm_bf16<<<dim3(2,128,4), dim3(256), 0, stream>>>(
      xn_b, NC, 128, wb_in, 128, 256*128, 128,
      xc4, 128, zg4, 128, 128, (long)NTOK*128,
      (float*)nullptr, 0, (const float*)nullptr);

  k_convxp<<<dim3(NTOK/64,1,4), dim3(256), 0, stream>>>(
      xc4, conv_w, conv_b, wb_xp, u4b, xd4);

  k_scan1<<<dim3(16*NCH,1,4), dim3(128), 0, stream>>>(
      u4b, xd4, A_log, dt_proj_w, dt_proj_b, chA, chB);
  k_scomb<<<dim3(16,1,4), dim3(128), 0, stream>>>(chA, chB, hIn);
  k_scan3<<<dim3(16*NCH,1,4), dim3(128), 0, stream>>>(
      u4b, xd4, A_log, dt_proj_w, dt_proj_b, D_param, hIn, y4b);

  k_yo<<<dim3(NTOK/16,1,4), dim3(256), 0, stream>>>(
      y4b, zg4, out_norm_w, out_norm_b, yo4);

  // out_proj (batched)
  k_gemm_bf16<<<dim3(1,128,4), dim3(256), 0, stream>>>(
      yo4, 128, (long)NTOK*128, wb_out, 128, 128*128, 128,
      ybuf_b, NC, ybuf_b, NC, 1<<30, 128,
      (float*)nullptr, 0, (const float*)nullptr);

  k_gateln<<<dim3(NTOK/4), dim3(256), 0, stream>>>(
      ybuf_b, xn_b, gatep, skip_scale, norm_w, norm_b, xmn_b);

  // final proj -> out (fp32)
  k_gemm_bf16<<<dim3(4,128,1), dim3(256), 0, stream>>>(
      xmn_b, NC, 0, wb_prj, NC, 0, NC,
      (ushort*)nullptr, 0, (ushort*)nullptr, 0, 0, 0,
      out, NC, proj_b);
}

// Round 8
// 136.329 us; speedup vs baseline: 6.3580x; 1.3469x over previous
//
#include <hip/hip_runtime.h>
#include <math.h>

// B=16, H=W=32, C=512, D=128/group, S=1, R=8
#define NTOK 16384
#define NC 512
#define ND 128
#define NCH 64   // scan chunks per (b,g)
#define CST 16   // steps per chunk

typedef __attribute__((ext_vector_type(8))) short bf16x8;
typedef __attribute__((ext_vector_type(4))) float f32x4;

#define LOG2E 1.4426950408889634f
#define LN2   0.6931471805599453f

// fast e^x via single v_exp_f32 (exp2)
__device__ __forceinline__ float fexp(float x){ return __builtin_amdgcn_exp2f(x * LOG2E); }
// fast ln via single v_log_f32 (log2)
__device__ __forceinline__ float flog(float x){ return __builtin_amdgcn_logf(x) * LN2; }
__device__ __forceinline__ float sigf(float x){ return 1.f/(1.f + fexp(-x)); }

__device__ __forceinline__ float b2f(ushort u){ unsigned x = ((unsigned)u)<<16; return __builtin_bit_cast(float,x); }
__device__ __forceinline__ ushort f2b(float f){
  unsigned u = __builtin_bit_cast(unsigned,f);
  u += 0x7fff + ((u>>16)&1);
  return (ushort)(u>>16);
}

__device__ __forceinline__ int perm_pos(int g, int l){
  switch(g){
    case 0: return l;
    case 1: return ((l & 31) << 5) | (l >> 5);
    case 2: return 1023 - l;
    default:{ int ll = 1023 - l; return ((ll & 31) << 5) | (ll >> 5); }
  }
}

__device__ __forceinline__ void gload16(const void* g, void* l){
  __builtin_amdgcn_global_load_lds((const __attribute__((address_space(1))) void*)g,
                                   (__attribute__((address_space(3))) void*)l, 16, 0, 0);
}

// ---------------- fp32 -> bf16 convert, 4 arrays in one launch ----------------
__global__ __launch_bounds__(256) void k_tobf16_4(
    const float* __restrict__ s1, int n1, ushort* __restrict__ d1,
    const float* __restrict__ s2, int n2, ushort* __restrict__ d2,
    const float* __restrict__ s3, int n3, ushort* __restrict__ d3,
    const float* __restrict__ s4, int n4, ushort* __restrict__ d4){
  int i = blockIdx.x*256 + threadIdx.x;
  if (i < n1) d1[i] = f2b(s1[i]);
  else if (i < n1+n2) d2[i-n1] = f2b(s2[i-n1]);
  else if (i < n1+n2+n3) d3[i-n1-n2] = f2b(s3[i-n1-n2]);
  else if (i < n1+n2+n3+n4) d4[i-n1-n2-n3] = f2b(s4[i-n1-n2-n3]);
}

// ---------------- K1: LayerNorm over C=512, wave-per-token, bf16 out ----------------
__global__ __launch_bounds__(256) void k_ln512(const float* __restrict__ x,
    const float* __restrict__ w, const float* __restrict__ b, ushort* __restrict__ out){
  int wv = threadIdx.x >> 6, lane = threadIdx.x & 63;
  int t = blockIdx.x*4 + wv;
  const float* xr = x + (size_t)t*NC + lane*8;
  float4 a = *(const float4*)xr;
  float4 c = *(const float4*)(xr+4);
  float e[8] = {a.x,a.y,a.z,a.w,c.x,c.y,c.z,c.w};
  float s = 0.f, sq = 0.f;
  #pragma unroll
  for (int i=0;i<8;i++){ s += e[i]; sq += e[i]*e[i]; }
  #pragma unroll
  for (int o=1;o<64;o<<=1){ s += __shfl_xor(s,o); sq += __shfl_xor(sq,o); }
  float m = s*(1.f/NC);
  float var = sq*(1.f/NC) - m*m;
  float rs = rsqrtf(var + 1e-5f);
  const float4* wr = (const float4*)(w + lane*8);
  const float4* br = (const float4*)(b + lane*8);
  float4 w0 = wr[0], w1 = wr[1], b0 = br[0], b1 = br[1];
  float wv8[8] = {w0.x,w0.y,w0.z,w0.w,w1.x,w1.y,w1.z,w1.w};
  float bv8[8] = {b0.x,b0.y,b0.z,b0.w,b1.x,b1.y,b1.z,b1.w};
  bf16x8 o8;
  #pragma unroll
  for (int i=0;i<8;i++) ((ushort*)&o8)[i] = f2b((e[i]-m)*rs*wv8[i]+bv8[i]);
  *(bf16x8*)(out + (size_t)t*NC + lane*8) = o8;
}

// ---------------- K2: column mean, 2-stage ----------------
__global__ __launch_bounds__(512) void k_cm1(const ushort* __restrict__ xn,
    float* __restrict__ part){
  int c = threadIdx.x;
  const ushort* base = xn + ((size_t)blockIdx.x*32)*NC + c;
  float acc = 0.f;
  for (int n=0;n<32;n++) acc += b2f(base[(size_t)n*NC]);
  part[(size_t)blockIdx.x*NC + c] = acc;
}
__global__ __launch_bounds__(512) void k_cm2(const float* __restrict__ part,
    float* __restrict__ zavg){
  int b = blockIdx.x, c = threadIdx.x;
  float acc = 0.f;
  for (int i=0;i<32;i++) acc += part[(size_t)(b*32+i)*NC + c];
  zavg[b*NC+c] = acc * (1.f/1024.f);
}

// ---------------- K3: ECA + FC gate; wave-per-output, coalesced ----------------
__global__ __launch_bounds__(256) void k_gate(const float* __restrict__ zavg,
    const float* __restrict__ fcw, const float* __restrict__ fcb,
    const float* __restrict__ ew, float* __restrict__ gate){
  __shared__ float za[NC];
  int b = blockIdx.x >> 7, og = blockIdx.x & 127;
  int tid = threadIdx.x, lane = tid & 63, wv = tid >> 6;
  za[tid]     = zavg[b*NC + tid];
  za[tid+256] = zavg[b*NC + tid + 256];
  __syncthreads();
  int o = og*4 + wv;
  const float* wr = fcw + (size_t)o*NC;
  float acc = 0.f;
  #pragma unroll
  for (int i=0;i<8;i++) acc += za[lane + i*64]*wr[lane + i*64];
  #pragma unroll
  for (int off=1;off<64;off<<=1) acc += __shfl_xor(acc, off);
  if (lane==0){
    float left  = (o>0)    ? za[o-1] : 0.f;
    float right = (o<NC-1) ? za[o+1] : 0.f;
    float ye = ew[0]*left + ew[1]*za[o] + ew[2]*right;
    gate[b*NC+o] = sigf(acc + fcb[o] + ye);
  }
}

// ---------------- K4: bf16 MFMA GEMM, z-batched ----------------
__global__ __launch_bounds__(256) void k_gemm_bf16(
    const ushort* __restrict__ A, int lda, long sAz,
    const ushort* __restrict__ Bw, int ldb, long sBz, int K,
    ushort* __restrict__ C0, int ldc0, ushort* __restrict__ C1, int ldc1,
    int nsplit, long sCz,
    float* __restrict__ Cf, int ldcf, const float* __restrict__ bias)
{
  __shared__ __align__(16) ushort Asm[128*64];
  __shared__ __align__(16) ushort Bsm[128*64];
  const int z = blockIdx.z;
  A  += (size_t)z*sAz;
  Bw += (size_t)z*sBz;
  if (C0) C0 += (size_t)z*sCz;
  if (C1) C1 += (size_t)z*sCz;
  const int tid = threadIdx.x;
  const int lane = tid & 63, wid = tid >> 6;
  const int wm = wid >> 1, wn = wid & 1;
  const int m0 = blockIdx.y * 128, n0 = blockIdx.x * 128;

  const ushort* ga[4]; const ushort* gb[4]; int ldst[4];
  #pragma unroll
  for (int j=0;j<4;j++){
    int c = tid + 256*j;
    int r = c >> 3;
    int kb = ((c & 7) << 4) ^ ((r & 7) << 4);
    ga[j] = A  + (size_t)(m0 + r)*lda + (kb >> 1);
    gb[j] = Bw + (size_t)(n0 + r)*ldb + (kb >> 1);
    ldst[j] = c * 8;
  }

  f32x4 acc[4][4];
  #pragma unroll
  for (int i=0;i<4;i++)
    #pragma unroll
    for (int j=0;j<4;j++) acc[i][j] = (f32x4){0.f,0.f,0.f,0.f};

  const int lc = lane & 15;
  const int kgrp = (lane >> 4) << 4;

  for (int k0 = 0; k0 < K; k0 += 64){
    #pragma unroll
    for (int j=0;j<4;j++) gload16(ga[j] + k0, Asm + ldst[j]);
    #pragma unroll
    for (int j=0;j<4;j++) gload16(gb[j] + k0, Bsm + ldst[j]);
    __syncthreads();
    #pragma unroll
    for (int kk=0; kk<2; kk++){
      bf16x8 af[4], bfr[4];
      #pragma unroll
      for (int i=0;i<4;i++){
        int ra = wm*64 + i*16 + lc;
        int kb = kk*64 + kgrp;
        af[i] = *(const bf16x8*)((const char*)Asm + ra*128 + (kb ^ ((ra&7)<<4)));
        int rb = wn*64 + i*16 + lc;
        bfr[i] = *(const bf16x8*)((const char*)Bsm + rb*128 + (kb ^ ((rb&7)<<4)));
      }
      #pragma unroll
      for (int i=0;i<4;i++)
        #pragma unroll
        for (int j=0;j<4;j++)
          acc[i][j] = __builtin_amdgcn_mfma_f32_16x16x32_bf16(af[i], bfr[j], acc[i][j], 0, 0, 0);
    }
    __syncthreads();
  }

  const int lr = (lane >> 4) * 4;
  if (Cf){
    #pragma unroll
    for (int i=0;i<4;i++)
      #pragma unroll
      for (int j=0;j<4;j++){
        int row = m0 + wm*64 + i*16 + lr;
        int col = n0 + wn*64 + j*16 + lc;
        float bv = bias ? bias[col] : 0.f;
        #pragma unroll
        for (int r=0;r<4;r++)
          Cf[(size_t)(row+r)*ldcf + col] = acc[i][j][r] + bv;
      }
  } else {
    #pragma unroll
    for (int i=0;i<4;i++)
      #pragma unroll
      for (int j=0;j<4;j++){
        int row = m0 + wm*64 + i*16 + lr;
        int col = n0 + wn*64 + j*16 + lc;
        #pragma unroll
        for (int r=0;r<4;r++){
          ushort hv = f2b(acc[i][j][r]);
          if (col < nsplit) C0[(size_t)(row+r)*ldc0 + col] = hv;
          else              C1[(size_t)(row+r)*ldc1 + col - nsplit] = hv;
        }
      }
  }
}

// ---------------- K5: conv3x3+SiLU from LDS-staged halo + x_proj via MFMA ----------------
__global__ __launch_bounds__(256) void k_convxp(const ushort* __restrict__ xc,
    const float* __restrict__ cw, const float* __restrict__ cb,
    const ushort* __restrict__ xpw_b, ushort* __restrict__ u, float* __restrict__ xd){
  __shared__ __align__(16) ushort xin[4*32*128];   // 32 KB halo window
  __shared__ __align__(16) ushort su[64][136];     // conv output for x_proj
  int g = blockIdx.z, tid = threadIdx.x;
  int blk = blockIdx.x;
  int bimg = blk >> 4, rp = blk & 15;
  int t0 = blk * 64;
  const ushort* xcg = xc + (size_t)g*NTOK*ND;

  #pragma unroll
  for (int j=0;j<8;j++){
    int c = tid + 256*j;          // 0..2047
    int r = c >> 9;               // local row 0..3
    int rest = c & 511;
    int gr = 2*rp + r - 1;
    gr = min(max(gr, 0), 31);     // clamp; invalid rows never read by conv
    int w = rest >> 4, p = rest & 15;
    gload16(xcg + ((size_t)((bimg<<10) | (gr<<5) | w))*ND + p*8, (ushort*)xin + c*8);
  }

  int p = tid & 15, d0 = p*8;
  float w_[9][8]; float bias[8];
  {
    const float* wk = cw + (size_t)(g*ND + d0)*9;
    #pragma unroll
    for (int j=0;j<8;j++)
      #pragma unroll
      for (int k9=0;k9<9;k9++) w_[k9][j] = wk[j*9+k9];
    const float* cbp = cb + g*ND + d0;
    #pragma unroll
    for (int j=0;j<8;j++) bias[j] = cbp[j];
  }
  __syncthreads();

  #pragma unroll
  for (int pass=0; pass<4; pass++){
    int lt = pass*16 + (tid>>4);
    int hl = lt >> 5, w = lt & 31;
    int t = t0 + lt;
    float acc[8];
    #pragma unroll
    for (int j=0;j<8;j++) acc[j] = bias[j];
    #pragma unroll
    for (int kh=0;kh<3;kh++){
      int gr = 2*rp + hl + kh - 1;
      if (gr < 0 || gr >= 32) continue;
      #pragma unroll
      for (int kw=0;kw<3;kw++){
        int w2 = w + kw - 1;
        if (w2 < 0 || w2 >= 32) continue;
        bf16x8 v = *(const bf16x8*)&xin[((hl+kh)*32 + w2)*128 + d0];
        #pragma unroll
        for (int j=0;j<8;j++) acc[j] = fmaf(b2f(((ushort*)&v)[j]), w_[kh*3+kw][j], acc[j]);
      }
    }
    bf16x8 o8;
    #pragma unroll
    for (int j=0;j<8;j++){
      float uv = acc[j] * sigf(acc[j]);
      ((ushort*)&o8)[j] = f2b(uv);
    }
    *(bf16x8*)(u + ((size_t)g*NTOK + t)*ND + d0) = o8;
    *(bf16x8*)&su[lt][d0] = o8;
  }
  __syncthreads();

  int lane = tid & 63, wv = tid >> 6;
  int c = lane & 15;
  int kg = (lane >> 4) * 8;
  int cc = c < 10 ? c : 0;
  f32x4 acc4 = (f32x4){0.f,0.f,0.f,0.f};
  #pragma unroll
  for (int ks=0; ks<4; ks++){
    bf16x8 af = *(const bf16x8*)&su[wv*16 + (lane & 15)][ks*32 + kg];
    bf16x8 bfv = *(const bf16x8*)(xpw_b + (size_t)(g*10+cc)*128 + ks*32 + kg);
    if (c >= 10) bfv = (bf16x8){0,0,0,0,0,0,0,0};
    acc4 = __builtin_amdgcn_mfma_f32_16x16x32_bf16(af, bfv, acc4, 0, 0, 0);
  }
  if (c < 10){
    #pragma unroll
    for (int r=0;r<4;r++){
      int row = (lane >> 4)*4 + r;
      int t = t0 + wv*16 + row;
      xd[((size_t)g*NTOK + t)*12 + c] = acc4[r];
    }
  }
}

// ---------------- scan helpers ----------------
struct ScanCtx {
  float Ad, dtb_d;
  float w[8];
};

__device__ __forceinline__ void scan_step(const ScanCtx& c, float uv,
    const float4& x0, const float4& x1, float Bv,
    float& h, float& ap){
  float a = c.dtb_d;
  a = fmaf(x0.x, c.w[0], a); a = fmaf(x0.y, c.w[1], a);
  a = fmaf(x0.z, c.w[2], a); a = fmaf(x0.w, c.w[3], a);
  a = fmaf(x1.x, c.w[4], a); a = fmaf(x1.y, c.w[5], a);
  a = fmaf(x1.z, c.w[6], a); a = fmaf(x1.w, c.w[7], a);
  // fast softplus: log(1+e^a) via single v_exp + v_log
  float dl = (a > 15.f) ? a : flog(1.f + fexp(a));
  float av = fexp(dl * c.Ad);
  h = fmaf(av, h, dl*Bv*uv);
  ap *= av;
}

// ---------------- K6: scan pass 1 ----------------
__global__ __launch_bounds__(128) void k_scan1(const ushort* __restrict__ u,
    const float* __restrict__ xd, const float* __restrict__ Alog,
    const float* __restrict__ dtw, const float* __restrict__ dtb,
    float* __restrict__ chA, float* __restrict__ chB){
  int d = threadIdx.x, g = blockIdx.z;
  int b = blockIdx.x >> 6, ch = blockIdx.x & 63;
  ScanCtx c;
  c.Ad = -fexp(Alog[g*ND+d]);
  c.dtb_d = dtb[g*ND+d];
  const float4* wr = (const float4*)(dtw + (size_t)(g*ND+d)*8);
  float4 w0 = wr[0], w1 = wr[1];
  c.w[0]=w0.x;c.w[1]=w0.y;c.w[2]=w0.z;c.w[3]=w0.w;
  c.w[4]=w1.x;c.w[5]=w1.y;c.w[6]=w1.z;c.w[7]=w1.w;
  float h = 0.f, ap = 1.f;
  int l0 = ch*CST;
  #pragma unroll 4
  for (int s=0;s<CST;s++){
    int pp = perm_pos(g, l0 + s);
    size_t base = (size_t)g*NTOK + ((b<<10)|pp);
    float uv = b2f(u[base*ND + d]);
    const float4* xr = (const float4*)(xd + base*12);
    float4 x0 = xr[0], x1 = xr[1], x2 = xr[2];
    scan_step(c, uv, x0, x1, x2.x, h, ap);
  }
  size_t o = (((size_t)g*16 + b)*NCH + ch)*ND + d;
  chA[o]=ap; chB[o]=h;
}

// ---------------- K7: combine over chunks ----------------
__global__ __launch_bounds__(128) void k_scomb(const float* __restrict__ chA,
    const float* __restrict__ chB, float* __restrict__ hIn){
  int b = blockIdx.x, g = blockIdx.z, d = threadIdx.x;
  size_t base = (((size_t)g*16 + b)*NCH)*ND + d;
  float hrun = 0.f;
  #pragma unroll
  for (int ch=0; ch<NCH; ch++){
    size_t o = base + (size_t)ch*ND;
    float a = chA[o], bb = chB[o];
    hIn[o] = hrun;
    hrun = fmaf(a, hrun, bb);
  }
}

// ---------------- K8: scan pass 3 (bf16 y out) ----------------
__global__ __launch_bounds__(128) void k_scan3(const ushort* __restrict__ u,
    const float* __restrict__ xd, const float* __restrict__ Alog,
    const float* __restrict__ dtw, const float* __restrict__ dtb,
    const float* __restrict__ Dp, const float* __restrict__ hIn,
    ushort* __restrict__ y){
  int d = threadIdx.x, g = blockIdx.z;
  int b = blockIdx.x >> 6, ch = blockIdx.x & 63;
  ScanCtx c;
  c.Ad = -fexp(Alog[g*ND+d]);
  c.dtb_d = dtb[g*ND+d];
  float Dd = Dp[g*ND+d];
  const float4* wr = (const float4*)(dtw + (size_t)(g*ND+d)*8);
  float4 w0 = wr[0], w1 = wr[1];
  c.w[0]=w0.x;c.w[1]=w0.y;c.w[2]=w0.z;c.w[3]=w0.w;
  c.w[4]=w1.x;c.w[5]=w1.y;c.w[6]=w1.z;c.w[7]=w1.w;
  float h = hIn[(((size_t)g*16 + b)*NCH + ch)*ND + d];
  float ap = 1.f;
  int l0 = ch*CST;
  #pragma unroll 4
  for (int s=0;s<CST;s++){
    int pp = perm_pos(g, l0 + s);
    size_t base = (size_t)g*NTOK + ((b<<10)|pp);
    float uv = b2f(u[base*ND + d]);
    const float4* xr = (const float4*)(xd + base*12);
    float4 x0 = xr[0], x1 = xr[1], x2 = xr[2];
    scan_step(c, uv, x0, x1, x2.x, h, ap);
    y[base*ND + d] = f2b(fmaf(h, x2.y, Dd*uv));
  }
}

// ---------------- K9: out-LN(128) * SiLU(z); bf16 in/out ----------------
__global__ __launch_bounds__(256) void k_yo(const ushort* __restrict__ y,
    const ushort* __restrict__ zg, const float* __restrict__ onw,
    const float* __restrict__ onb, ushort* __restrict__ yo){
  int tid = threadIdx.x, g = blockIdx.z;
  int lt = tid >> 4, p = tid & 15;
  int t = blockIdx.x*16 + lt;
  size_t base = ((size_t)g*NTOK + t)*ND + p*8;
  bf16x8 yv8 = *(const bf16x8*)(y + base);
  float e[8];
  float s = 0.f, sq = 0.f;
  #pragma unroll
  for (int i=0;i<8;i++){
    e[i] = b2f(((ushort*)&yv8)[i]);
    s += e[i]; sq += e[i]*e[i];
  }
  #pragma unroll
  for (int o=1;o<16;o<<=1){ s += __shfl_xor(s,o); sq += __shfl_xor(sq,o); }
  float m = s*(1.f/ND);
  float var = sq*(1.f/ND) - m*m;
  float rs = rsqrtf(var + 1e-5f);
  const float4* wr = (const float4*)(onw + g*ND + p*8);
  const float4* br = (const float4*)(onb + g*ND + p*8);
  float4 w0 = wr[0], w1 = wr[1], b0 = br[0], b1 = br[1];
  float wv8[8] = {w0.x,w0.y,w0.z,w0.w,w1.x,w1.y,w1.z,w1.w};
  float bv8[8] = {b0.x,b0.y,b0.z,b0.w,b1.x,b1.y,b1.z,b1.w};
  bf16x8 zv = *(const bf16x8*)(zg + base);
  bf16x8 o8;
  #pragma unroll
  for (int i=0;i<8;i++){
    float yn = (e[i]-m)*rs*wv8[i]+bv8[i];
    float z = b2f(((ushort*)&zv)[i]);
    ((ushort*)&o8)[i] = f2b(yn * z * sigf(z));
  }
  *(bf16x8*)(yo + base) = o8;
}

// ---------------- K10: skip*xh*gate then LN(512); wave-per-token ----------------
__global__ __launch_bounds__(256) void k_gateln(const ushort* __restrict__ ybuf,
    const ushort* __restrict__ xn, const float* __restrict__ gate,
    const float* __restrict__ skip, const float* __restrict__ w,
    const float* __restrict__ b, ushort* __restrict__ out){
  int wv = threadIdx.x >> 6, lane = threadIdx.x & 63;
  int t = blockIdx.x*4 + wv, bb = t >> 10;
  float ss = skip[0];
  size_t o0 = (size_t)t*NC + lane*8;
  bf16x8 yv = *(const bf16x8*)(ybuf + o0);
  bf16x8 xv = *(const bf16x8*)(xn + o0);
  const float4* gr = (const float4*)(gate + bb*NC + lane*8);
  float4 g0 = gr[0], g1 = gr[1];
  float gv8[8] = {g0.x,g0.y,g0.z,g0.w,g1.x,g1.y,g1.z,g1.w};
  float e[8];
  float s = 0.f, sq = 0.f;
  #pragma unroll
  for (int i=0;i<8;i++){
    e[i] = b2f(((ushort*)&yv)[i]) * ss * b2f(((ushort*)&xv)[i]) * gv8[i];
    s += e[i]; sq += e[i]*e[i];
  }
  #pragma unroll
  for (int o=1;o<64;o<<=1){ s += __shfl_xor(s,o); sq += __shfl_xor(sq,o); }
  float m = s*(1.f/NC);
  float var = sq*(1.f/NC) - m*m;
  float rs = rsqrtf(var + 1e-5f);
  const float4* wr = (const float4*)(w + lane*8);
  const float4* br = (const float4*)(b + lane*8);
  float4 w0 = wr[0], w1 = wr[1], b0 = br[0], b1 = br[1];
  float wv8[8] = {w0.x,w0.y,w0.z,w0.w,w1.x,w1.y,w1.z,w1.w};
  float bv8[8] = {b0.x,b0.y,b0.z,b0.w,b1.x,b1.y,b1.z,b1.w};
  bf16x8 o8;
  #pragma unroll
  for (int i=0;i<8;i++) ((ushort*)&o8)[i] = f2b((e[i]-m)*rs*wv8[i]+bv8[i]);
  *(bf16x8*)(out + o0) = o8;
}

extern "C" void kernel_launch(void* const* d_in, const int* in_sizes, int n_in,
                              void* d_out, int out_size, void* d_ws, size_t ws_size,
                              hipStream_t stream) {
  const float* x          = (const float*)d_in[0];
  const float* norm_w     = (const float*)d_in[3];
  const float* norm_b     = (const float*)d_in[4];
  const float* fc_w       = (const float*)d_in[5];
  const float* fc_b       = (const float*)d_in[6];
  const float* eca_w      = (const float*)d_in[7];
  const float* skip_scale = (const float*)d_in[8];
  const float* proj_w     = (const float*)d_in[9];
  const float* proj_b     = (const float*)d_in[10];
  const float* in_proj_w  = (const float*)d_in[11];
  const float* conv_w     = (const float*)d_in[12];
  const float* conv_b     = (const float*)d_in[13];
  const float* x_proj_w   = (const float*)d_in[14];
  const float* dt_proj_w  = (const float*)d_in[15];
  const float* dt_proj_b  = (const float*)d_in[16];
  const float* A_log      = (const float*)d_in[17];
  const float* D_param    = (const float*)d_in[18];
  const float* out_norm_w = (const float*)d_in[19];
  const float* out_norm_b = (const float*)d_in[20];
  const float* out_proj_w = (const float*)d_in[21];
  float* out = (float*)d_out;
  float* ws  = (float*)d_ws;

  // ---- workspace layout (float units) — disjoint intervals ----
  ushort* xn_b   = (ushort*)(ws);                  // [0,        4194304)
  ushort* ybuf_b = (ushort*)(ws + 4194304);        // [4194304,  8388608)
  ushort* xc4    = (ushort*)(ws + 8388608);        // [8388608, 12582912)
  ushort* zg4    = (ushort*)(ws + 12582912);       // [12582912,16777216)
  ushort* yo4    = (ushort*)(ws + 16777216);       // [16777216,20971520)
  ushort* u4b    = (ushort*)(ws + 20971520);       // [20971520,25165824)
  ushort* y4b    = (ushort*)(ws + 25165824);       // [25165824,29360128)
  float*  xd4    = ws + 29360128;                  // [29360128,30146560)
  float*  chA    = ws + 30146560;                  // [30146560,30670848)
  float*  chB    = ws + 30670848;                  // [30670848,31195136)
  float*  hIn    = ws + 31195136;                  // [31195136,31719424)
  float*  zavg   = ws + 31719424;                  // +8192
  float*  gatep  = ws + 31727616;                  // +8192
  float*  part   = ws + 31735808;                  // +262144 -> 31997952
  ushort* wb_in  = (ushort*)(ws + 31997952);       // 131072 bf16
  ushort* wb_out = (ushort*)(ws + 32063488);       // 65536 bf16
  ushort* wb_prj = (ushort*)(ws + 32096256);       // 262144 bf16
  ushort* wb_xp  = (ushort*)(ws + 32227328);       // 5120 bf16
  ushort* xmn_b  = (ushort*)(ws + 32229888);       // [32229888,36424192)

  k_ln512<<<dim3(NTOK/4), dim3(256), 0, stream>>>(x, norm_w, norm_b, xn_b);
  k_cm1<<<dim3(512), dim3(512), 0, stream>>>(xn_b, part);
  k_cm2<<<dim3(16), dim3(512), 0, stream>>>(part, zavg);
  k_gate<<<dim3(16*128), dim3(256), 0, stream>>>(zavg, fc_w, fc_b, eca_w, gatep);
  k_tobf16_4<<<dim3(1812), dim3(256), 0, stream>>>(
      in_proj_w, 131072, wb_in, out_proj_w, 65536, wb_out,
      proj_w, 262144, wb_prj, x_proj_w, 5120, wb_xp);

  // in_proj (batched over g)
  k_gemm_bf16<<<dim3(2,128,4), dim3(256), 0, stream>>>(
      xn_b, NC, 128, wb_in, 128, 256*128, 128,
      xc4, 128, zg4, 128, 128, (long)NTOK*128,
      (float*)nullptr, 0, (const float*)nullptr);

  k_convxp<<<dim3(NTOK/64,1,4), dim3(256), 0, stream>>>(
      xc4, conv_w, conv_b, wb_xp, u4b, xd4);

  k_scan1<<<dim3(16*NCH,1,4), dim3(128), 0, stream>>>(
      u4b, xd4, A_log, dt_proj_w, dt_proj_b, chA, chB);
  k_scomb<<<dim3(16,1,4), dim3(128), 0, stream>>>(chA, chB, hIn);
  k_scan3<<<dim3(16*NCH,1,4), dim3(128), 0, stream>>>(
      u4b, xd4, A_log, dt_proj_w, dt_proj_b, D_param, hIn, y4b);

  k_yo<<<dim3(NTOK/16,1,4), dim3(256), 0, stream>>>(
      y4b, zg4, out_norm_w, out_norm_b, yo4);

  // out_proj (batched)
  k_gemm_bf16<<<dim3(1,128,4), dim3(256), 0, stream>>>(
      yo4, 128, (long)NTOK*128, wb_out, 128, 128*128, 128,
      ybuf_b, NC, ybuf_b, NC, 1<<30, 128,
      (float*)nullptr, 0, (const float*)nullptr);

  k_gateln<<<dim3(NTOK/4), dim3(256), 0, stream>>>(
      ybuf_b, xn_b, gatep, skip_scale, norm_w, norm_b, xmn_b);

  // final proj -> out (fp32)
  k_gemm_bf16<<<dim3(4,128,1), dim3(256), 0, stream>>>(
      xmn_b, NC, 0, wb_prj, NC, 0, NC,
      (ushort*)nullptr, 0, (ushort*)nullptr, 0, 0, 0,
      out, NC, proj_b);
}